// Round 13
// baseline (1415.716 us; speedup 1.0000x reference)
//
#include <hip/hip_runtime.h>
#include <cfloat>
#include <cmath>

#define B_ 4
#define N_ 16384
#define M_ 512
#define C_ 128
#define K_ 16
#define L_ 6
#define STEPS_ 5

#define GC_ 32
#define NC_ (GC_ * GC_ * GC_)
#define LO_ (-5.2f)
#define H_ (10.4f / 32.0f)
#define INVH_ (32.0f / 10.4f)
#define CAPS_ 192
#define CAPM_ 175

// ---------------- wave helpers (wave64) ----------------
__device__ inline int wave_sum_i(int v) {
#pragma unroll
  for (int m = 1; m < 64; m <<= 1) v += __shfl_xor(v, m, 64);
  return v;
}
__device__ __forceinline__ unsigned long long bsort64(unsigned long long v) {
  int lane = threadIdx.x & 63;
#pragma unroll
  for (int k = 2; k <= 64; k <<= 1) {
#pragma unroll
    for (int j = k >> 1; j > 0; j >>= 1) {
      unsigned long long o = __shfl_xor(v, j, 64);
      bool keepmin = (((lane & k) == 0) == ((lane & j) == 0));
      unsigned long long mn = v < o ? v : o;
      unsigned long long mx = v < o ? o : v;
      v = keepmin ? mn : mx;
    }
  }
  return v;
}
__device__ __forceinline__ void bsort64x2(unsigned long long& v0,
                                          unsigned long long& v1) {
  int lane = threadIdx.x & 63;
#pragma unroll
  for (int k = 2; k <= 64; k <<= 1) {
#pragma unroll
    for (int j = k >> 1; j > 0; j >>= 1) {
      bool keepmin = (((lane & k) == 0) == ((lane & j) == 0));
      unsigned long long o0 = __shfl_xor(v0, j, 64);
      unsigned long long o1 = __shfl_xor(v1, j, 64);
      v0 = keepmin ? (v0 < o0 ? v0 : o0) : (v0 < o0 ? o0 : v0);
      v1 = keepmin ? (v1 < o1 ? v1 : o1) : (v1 < o1 ? o1 : v1);
    }
  }
}
__device__ __forceinline__ void bsort64x3(unsigned long long& v0,
                                          unsigned long long& v1,
                                          unsigned long long& v2) {
  int lane = threadIdx.x & 63;
#pragma unroll
  for (int k = 2; k <= 64; k <<= 1) {
#pragma unroll
    for (int j = k >> 1; j > 0; j >>= 1) {
      bool keepmin = (((lane & k) == 0) == ((lane & j) == 0));
      unsigned long long o0 = __shfl_xor(v0, j, 64);
      unsigned long long o1 = __shfl_xor(v1, j, 64);
      unsigned long long o2 = __shfl_xor(v2, j, 64);
      v0 = keepmin ? (v0 < o0 ? v0 : o0) : (v0 < o0 ? o0 : v0);
      v1 = keepmin ? (v1 < o1 ? v1 : o1) : (v1 < o1 ? o1 : v1);
      v2 = keepmin ? (v2 < o2 ? v2 : o2) : (v2 < o2 ? o2 : v2);
    }
  }
}
__device__ __forceinline__ void bsort64x4(unsigned long long& v0,
                                          unsigned long long& v1,
                                          unsigned long long& v2,
                                          unsigned long long& v3) {
  int lane = threadIdx.x & 63;
#pragma unroll
  for (int k = 2; k <= 64; k <<= 1) {
#pragma unroll
    for (int j = k >> 1; j > 0; j >>= 1) {
      bool keepmin = (((lane & k) == 0) == ((lane & j) == 0));
      unsigned long long o0 = __shfl_xor(v0, j, 64);
      unsigned long long o1 = __shfl_xor(v1, j, 64);
      unsigned long long o2 = __shfl_xor(v2, j, 64);
      unsigned long long o3 = __shfl_xor(v3, j, 64);
      v0 = keepmin ? (v0 < o0 ? v0 : o0) : (v0 < o0 ? o0 : v0);
      v1 = keepmin ? (v1 < o1 ? v1 : o1) : (v1 < o1 ? o1 : v1);
      v2 = keepmin ? (v2 < o2 ? v2 : o2) : (v2 < o2 ? o2 : v2);
      v3 = keepmin ? (v3 < o3 ? v3 : o3) : (v3 < o3 ? o3 : v3);
    }
  }
}
// merge two cross-lane-sorted ascending sequences (top-17 valid in each)
__device__ __forceinline__ unsigned long long merge_sorted(
    unsigned long long acc, unsigned long long neu) {
  int lane = threadIdx.x & 63;
  unsigned long long hi = __shfl(neu, 63 - lane, 64);
  unsigned long long v = (lane < 32) ? acc : hi;
#pragma unroll
  for (int j = 32; j > 0; j >>= 1) {
    unsigned long long o = __shfl_xor(v, j, 64);
    unsigned long long mn = v < o ? v : o;
    unsigned long long mx = v < o ? o : v;
    v = ((lane & j) == 0) ? mn : mx;
  }
  return v;
}
// exact smallest-17 of s_buf[0..cnt), cnt <= 192 (pure-shuffle tournament)
__device__ __forceinline__ void sel17(const unsigned long long* s_buf, int cnt,
                                      unsigned long long* s_out, int lane) {
  unsigned long long v0 = (lane < cnt) ? s_buf[lane] : ~0ull;
  if (cnt <= 64) {
    v0 = bsort64(v0);
    if (lane < 17) s_out[lane] = v0;
    return;
  }
  unsigned long long v1 = (lane + 64 < cnt) ? s_buf[lane + 64] : ~0ull;
  if (cnt <= 128) {
    bsort64x2(v0, v1);
    unsigned long long v = merge_sorted(v0, v1);
    if (lane < 17) s_out[lane] = v;
    return;
  }
  unsigned long long v2 = (lane + 128 < cnt) ? s_buf[lane + 128] : ~0ull;
  bsort64x3(v0, v1, v2);
  unsigned long long v = merge_sorted(v0, v1);
  v = merge_sorted(v, v2);
  if (lane < 17) s_out[lane] = v;
}
__device__ __forceinline__ float d2_exact(float px, float py, float pz,
                                          float qx, float qy, float qz) {
#pragma clang fp contract(off)
  float dx = px - qx, dy = py - qy, dz = pz - qz;
  float xx = dx * dx, yy = dy * dy, zz = dz * dz;
  return (xx + yy) + zz;
}
__device__ __forceinline__ int cell_of(float x) {
  int c = (int)floorf((x - LO_) * INVH_);
  return c < 0 ? 0 : (c > GC_ - 1 ? GC_ - 1 : c);
}

// ---------------- encoder ----------------
__global__ __launch_bounds__(256) void k_encode(
    const float* __restrict__ xyz, const float* __restrict__ w1,
    const float* __restrict__ b1, const float* __restrict__ w2,
    const float* __restrict__ b2, float* __restrict__ feats) {
  __shared__ __align__(16) float s_w2[128 * 68];
  __shared__ __align__(16) float s_xyz[32 * 3];
  __shared__ __align__(16) float s_h[32 * 68];
  int t = threadIdx.x;
  for (int i = t; i < 128 * 64; i += 256) {
    int c = i >> 6, j = i & 63;
    s_w2[c * 68 + j] = w2[i];
  }
  int p0 = blockIdx.x * 32;
  for (int i = t; i < 96; i += 256) s_xyz[i] = xyz[(size_t)p0 * 3 + i];
  __syncthreads();
  int p = t >> 3, q = t & 7;
  float x0 = s_xyz[p * 3], x1 = s_xyz[p * 3 + 1], x2 = s_xyz[p * 3 + 2];
#pragma unroll
  for (int cc = 0; cc < 8; ++cc) {
    int c = q * 8 + cc;
    float a = b1[c] + w1[c * 3] * x0 + w1[c * 3 + 1] * x1 + w1[c * 3 + 2] * x2;
    s_h[p * 68 + c] = fmaxf(a, 0.f);
  }
  __syncthreads();
#pragma unroll
  for (int cc = 0; cc < 16; ++cc) {
    int c = q + cc * 8;
    float acc = b2[c];
    const float* wr = &s_w2[c * 68];
    const float* hr = &s_h[p * 68];
#pragma unroll
    for (int j = 0; j < 64; j += 4) {
      float4 w4 = *(const float4*)&wr[j];
      float4 h4 = *(const float4*)&hr[j];
      acc += w4.x * h4.x + w4.y * h4.y + w4.z * h4.z + w4.w * h4.w;
    }
    feats[(size_t)(p0 + p) * 128 + c] = acc;
  }
}

// ---------------- weight transpose prep ----------------
__global__ __launch_bounds__(256) void k_prep(
    const float* __restrict__ w_in, const float* __restrict__ w_out,
    const float* __restrict__ rt_w1, const float* __restrict__ rt_w2,
    float* __restrict__ wT) {
  int m = blockIdx.y;
  int i = blockIdx.x * 256 + threadIdx.x;
  int j = i >> 7, c = i & 127;
  const float* src = (m == 0)   ? w_in
                     : (m == 1) ? w_in + 16384
                     : (m == 2) ? w_in + 32768
                     : (m == 3) ? w_out
                     : (m == 4) ? rt_w1
                                : rt_w2;
  wT[(size_t)m * 16384 + j * 128 + c] = src[(size_t)c * 128 + j];
}

// ---------------- mv1: q = feats @ beta^T + beta_b ----------------
__global__ __launch_bounds__(256) void k_mv1(const float* __restrict__ feats,
                                             const float* __restrict__ beta_w,
                                             const float* __restrict__ beta_b,
                                             float* __restrict__ qbuf) {
  __shared__ __align__(16) float s_ft[32 * 128];
  int t = threadIdx.x;
  size_t p0 = (size_t)blockIdx.x * 32;
  const float4* src = (const float4*)(feats + p0 * 128);
  for (int i = t; i < 1024; i += 256) ((float4*)s_ft)[i] = src[i];
  __syncthreads();
  int c = t & 127, ph = t >> 7;
  float acc[16];
  float bb = beta_b[c];
#pragma unroll
  for (int i = 0; i < 16; ++i) acc[i] = bb;
  for (int j = 0; j < 128; j += 4) {
    float4 w4 = *(const float4*)&beta_w[(size_t)c * 128 + j];
#pragma unroll
    for (int i = 0; i < 16; ++i) {
      float4 f4 = *(const float4*)&s_ft[(ph * 16 + i) * 128 + j];
      acc[i] += w4.x * f4.x + w4.y * f4.y + w4.z * f4.z + w4.w * f4.w;
    }
  }
#pragma unroll
  for (int i = 0; i < 16; ++i) qbuf[(p0 + ph * 16 + i) * 128 + c] = acc[i];
}

// ---------------- mv2: qg = q @ gamma (in-place), qb = tree(q.gamma_b) ----
__global__ __launch_bounds__(256) void k_mv2(float* __restrict__ qbuf,
                                             const float* __restrict__ gamma_w,
                                             const float* __restrict__ gamma_b,
                                             float* __restrict__ qb) {
  __shared__ __align__(16) float s_t[32 * 128];
  __shared__ __align__(16) float s_gb[128];
  int t = threadIdx.x;
  size_t p0 = (size_t)blockIdx.x * 32;
  const float4* src = (const float4*)(qbuf + p0 * 128);
  for (int i = t; i < 1024; i += 256) ((float4*)s_t)[i] = src[i];
  if (t < 128) s_gb[t] = gamma_b[t];
  __syncthreads();
  int c = t & 127, ph = t >> 7;
  float acc[16];
#pragma unroll
  for (int i = 0; i < 16; ++i) acc[i] = 0.f;
  for (int cp = 0; cp < 128; ++cp) {
    float gw = gamma_w[(size_t)cp * 128 + c];
#pragma unroll
    for (int i = 0; i < 16; ++i) acc[i] += s_t[(ph * 16 + i) * 128 + cp] * gw;
  }
#pragma unroll
  for (int i = 0; i < 16; ++i) qbuf[(p0 + ph * 16 + i) * 128 + c] = acc[i];
  if (t < 32) {
    const float* tr = &s_t[t * 128];
    float x[32];
#pragma unroll
    for (int i = 0; i < 32; ++i) {
      float a = tr[2 * i] * s_gb[2 * i] + tr[2 * i + 64] * s_gb[2 * i + 64];
      float b2 = tr[2 * i + 1] * s_gb[2 * i + 1] +
                 tr[2 * i + 65] * s_gb[2 * i + 65];
      x[i] = a + b2;
    }
#pragma unroll
    for (int w2 = 16; w2 >= 1; w2 >>= 1)
      for (int i = 0; i < w2; ++i) x[i] = x[2 * i] + x[2 * i + 1];
    qb[p0 + t] = x[0];
  }
}

// ---------------- grid build ----------------
__global__ __launch_bounds__(256) void k_flags(const int* __restrict__ start,
                                               int* __restrict__ flags) {
  int g = blockIdx.x * 256 + threadIdx.x;
  if (g < B_ * M_) {
    int b = g >> 9;
    flags[b * N_ + start[g]] = 1;
  }
}
__global__ __launch_bounds__(256) void k_gcount(const float* __restrict__ xyz,
                                                const int* __restrict__ flags,
                                                int* __restrict__ counts,
                                                int* __restrict__ countsU) {
  int i = blockIdx.x * 256 + threadIdx.x;
  int b = i >> 14;
  float x = xyz[(size_t)i * 3], y = xyz[(size_t)i * 3 + 1],
        z = xyz[(size_t)i * 3 + 2];
  int cid = (cell_of(x) * GC_ + cell_of(y)) * GC_ + cell_of(z);
  atomicAdd(&counts[b * NC_ + cid], 1);
  if (!flags[i]) atomicAdd(&countsU[b * NC_ + cid], 1);
}
__global__ __launch_bounds__(256) void k_gprefix(const int* __restrict__ counts,
                                                 int* __restrict__ cellStart,
                                                 int* __restrict__ cellCur) {
  __shared__ int part[256];
  int b = blockIdx.x, t = threadIdx.x;
  const int* cb = counts + b * NC_;
  int s = 0;
  for (int k = 0; k < NC_ / 256; ++k) s += cb[t * (NC_ / 256) + k];
  part[t] = s;
  __syncthreads();
  if (t == 0) {
    int r = 0;
    for (int i = 0; i < 256; ++i) {
      int v = part[i];
      part[i] = r;
      r += v;
    }
  }
  __syncthreads();
  int run = part[t];
  for (int k = 0; k < NC_ / 256; ++k) {
    int cidx = t * (NC_ / 256) + k;
    int v = cb[cidx];
    cellStart[b * (NC_ + 1) + cidx] = run;
    cellCur[b * NC_ + cidx] = run;
    run += v;
  }
  if (t == 255) cellStart[b * (NC_ + 1) + NC_] = run;
}
__global__ __launch_bounds__(256) void k_gscatter(const float* __restrict__ xyz,
                                                  const int* __restrict__ flags,
                                                  int* __restrict__ cellCur,
                                                  float4* __restrict__ sorted) {
  int i = blockIdx.x * 256 + threadIdx.x;
  int b = i >> 14, n = i & (N_ - 1);
  float x = xyz[(size_t)i * 3], y = xyz[(size_t)i * 3 + 1],
        z = xyz[(size_t)i * 3 + 2];
  int cid = (cell_of(x) * GC_ + cell_of(y)) * GC_ + cell_of(z);
  int dst = atomicAdd(&cellCur[b * NC_ + cid], 1);
  unsigned pid = (unsigned)n | (flags[i] ? 0x80000000u : 0u);
  sorted[(size_t)b * N_ + dst] = make_float4(x, y, z, __uint_as_float(pid));
}
// per-step side list; dedup via atomicExch step-tag (claim zeroed once per
// launch; tags 1..5 are distinct per step and never equal stale values)
__global__ __launch_bounds__(256) void k_side(const float* __restrict__ pos,
                                              const int* __restrict__ start,
                                              int* __restrict__ claim,
                                              float4* __restrict__ posM,
                                              int tag) {
  int g = blockIdx.x * 256 + threadIdx.x;
  if (g < B_ * M_) {
    int b = g >> 9, s = start[g];
    int old = atomicExch(&claim[b * N_ + s], tag);
    if (old != tag) {
      const float* pp = pos + ((size_t)b * N_ + s) * 3;
      posM[g] = make_float4(pp[0], pp[1], pp[2], __uint_as_float((unsigned)s));
    } else {
      posM[g] = make_float4(3e30f, 3e30f, 3e30f, __uint_as_float(0xffffffffu));
    }
  }
}

// point lookup: row = largest r with s_pref[r] <= p; clamped index
__device__ __forceinline__ float4 load_pt(const float4* sortb, bool brute,
                                          int p, int Rr,
                                          const int* s_pref, const int* s_st) {
  int off;
  if (brute) {
    off = p;
  } else if (Rr == 1) {
    off = s_st[0] + p;  // dense-center fast path (smin==0)
  } else {
    int lo = 0, hi = Rr - 1, rsel = 0;
    while (lo <= hi) {
      int mid = (lo + hi) >> 1;
      if (s_pref[mid] <= p) {
        rsel = mid;
        lo = mid + 1;
      } else
        hi = mid - 1;
    }
    off = s_st[rsel] + (p - s_pref[rsel]);
  }
  off = off < 0 ? 0 : (off > N_ - 1 ? N_ - 1 : off);
  return sortb[off];
}

// ---------------- fused selector: 5 rounds, 1 walker per 64-thread block ---
__global__ __launch_bounds__(64) void k_select5(
    const float* __restrict__ pos, const float* __restrict__ feats,
    const float* __restrict__ qg, const float* __restrict__ qbArr,
    const int* __restrict__ start, float* __restrict__ walks,
    const float4* __restrict__ sorted, const int* __restrict__ cellStart,
    const int* __restrict__ countsU, const float4* __restrict__ posM,
    const float* __restrict__ gumb) {
  __shared__ int s_st[232];
  __shared__ int s_pref[232];
  __shared__ unsigned long long s_buf[CAPS_ + 24];
  __shared__ unsigned long long s_top[17];
  __shared__ float s_gum[16];
  __shared__ int s_cnt;

  int lane = threadIdx.x;
  int g = blockIdx.x;
  int b = g >> 9, mm = g & (M_ - 1);
  int idx = start[g];
  walks[(size_t)g * 768 + lane] = feats[((size_t)b * N_ + idx) * 128 + lane];
  walks[(size_t)g * 768 + 64 + lane] =
      feats[((size_t)b * N_ + idx) * 128 + 64 + lane];

  const float4* sortb = sorted + (size_t)b * N_;
  const int* csb = cellStart + b * (NC_ + 1);
  const int* cub = countsU + b * NC_;

  for (int l = 0; l < L_ - 1; ++l) {
    float g0 = qg[((size_t)b * N_ + idx) * 128 + lane];
    float g1 = qg[((size_t)b * N_ + idx) * 128 + 64 + lane];
    float qbv = qbArr[(size_t)b * N_ + idx];
    const float* pp = pos + ((size_t)b * N_ + idx) * 3;
    float qx = pp[0], qy = pp[1], qz = pp[2];
    if (lane < 16)
      s_gum[lane] =
          gumb[(size_t)l * B_ * M_ * K_ + ((size_t)b * M_ + mm) * K_ + lane];
    // prefetch side list into registers (loads overlap phase A below)
    float4 sp[8];
#pragma unroll
    for (int k = 0; k < 8; ++k) sp[k] = posM[(b << 9) + lane + (k << 6)];
    __syncthreads();

    int ci = cell_of(qx), cj = cell_of(qy), ck = cell_of(qz);

    // ---- phase A: rings 0-2 in one pass; rare s=3..7 via early-exit ----
    int smin = -1, acc = 0;
    {
      int p0 = 0, p1 = 0, p2 = 0;
#pragma unroll
      for (int it = 0; it < 2; ++it) {
        int o = it * 64 + lane;
        if (o < 125) {
          int oz = o / 25, rem = o - oz * 25;
          int oy = rem / 5, ox = rem - oy * 5;
          int ax = ox - 2, ay = oy - 2, az = oz - 2;
          int cax = ax < 0 ? -ax : ax, cay = ay < 0 ? -ay : ay,
              caz = az < 0 ? -az : az;
          int ring = cax > cay ? cax : cay;
          ring = ring > caz ? ring : caz;
          int ii = ci + ax, jj = cj + ay, kk = ck + az;
          if ((unsigned)ii < GC_ && (unsigned)jj < GC_ && (unsigned)kk < GC_) {
            int cnt = cub[(ii * GC_ + jj) * GC_ + kk];
            if (ring == 0) p0 += cnt;
            else if (ring == 1) p1 += cnt;
            else p2 += cnt;
          }
        }
      }
#pragma unroll
      for (int m = 1; m < 64; m <<= 1) {
        p0 += __shfl_xor(p0, m, 64);
        p1 += __shfl_xor(p1, m, 64);
        p2 += __shfl_xor(p2, m, 64);
      }
      int u0 = p0, u1 = p0 + p1, u2 = u1 + p2;
      smin = (u0 >= 17) ? 0 : (u1 >= 17) ? 1 : (u2 >= 17) ? 2 : -1;
      acc = u2;
    }
    for (int s = 3; s <= 7 && smin < 0; ++s) {
      int Wd = 2 * s + 1, tot = Wd * Wd * Wd;
      int part = 0;
      for (int o = lane; o < tot; o += 64) {
        int oz = o / (Wd * Wd), rem = o - oz * (Wd * Wd);
        int oy = rem / Wd, ox = rem - oy * Wd;
        int ax = ox - s, ay = oy - s, az = oz - s;
        int cax = ax < 0 ? -ax : ax, cay = ay < 0 ? -ay : ay,
            caz = az < 0 ? -az : az;
        int mx = cax > cay ? cax : cay;
        mx = mx > caz ? mx : caz;
        if (mx != s) continue;
        int ii = ci + ax, jj = cj + ay, kk = ck + az;
        if ((unsigned)ii >= GC_ || (unsigned)jj >= GC_ || (unsigned)kk >= GC_)
          continue;
        part += cub[(ii * GC_ + jj) * GC_ + kk];
      }
      acc += wave_sum_i(part);
      if (acc >= 17) smin = s;
    }
    bool brute = smin < 0;

    // side keys from prefetched registers (pure ALU, no loads)
    unsigned long long skey[8];
#pragma unroll
    for (int k = 0; k < 8; ++k) {
      unsigned pid = __float_as_uint(sp[k].w);
      float d2s = d2_exact(sp[k].x, sp[k].y, sp[k].z, qx, qy, qz);
      skey[k] = (pid == 0xffffffffu)
                    ? ~0ull
                    : (((unsigned long long)__float_as_uint(d2s) << 32) | pid);
    }

    // ---- build z-run table for the cube ----
    int T = 0, Rr = 0;
    if (!brute) {
      int Wd = 2 * smin + 1;
      Rr = Wd * Wd;
      int klo = ck - smin, khi = ck + smin;
      if (klo < 0) klo = 0;
      if (khi > GC_ - 1) khi = GC_ - 1;
      int nch = (Rr + 63) >> 6;
      for (int c = 0; c < nch; ++c) {
        int r = c * 64 + lane;
        int len = 0, st = 0;
        if (r < Rr) {
          int di = r / Wd, dj = r - di * Wd;
          int ii = ci + di - smin, jj = cj + dj - smin;
          if ((unsigned)ii < GC_ && (unsigned)jj < GC_) {
            int base = (ii * GC_ + jj) * GC_;
            st = csb[base + klo];
            len = csb[base + khi + 1] - st;
          }
        }
        int scan = len;
#pragma unroll
        for (int off = 1; off < 64; off <<= 1) {
          int v = __shfl_up(scan, off, 64);
          if (lane >= off) scan += v;
        }
        if (r < Rr) {
          s_pref[r] = T + scan - len;
          s_st[r] = st;
        }
        T += __shfl(scan, 63, 64);
      }
      __syncthreads();
    } else {
      T = N_;
    }

    // ---- B1 ----
    if (!brute && T <= 256) {
      // DIRECT PATH: single scan -> registers -> pure-shuffle tournament.
      unsigned long long k0 = ~0ull, k1 = ~0ull, k2 = ~0ull, k3 = ~0ull;
      if (lane < T) {
        float4 pt = load_pt(sortb, false, lane, Rr, s_pref, s_st);
        unsigned pid = __float_as_uint(pt.w);
        if (!(pid & 0x80000000u)) {
          float d2 = d2_exact(pt.x, pt.y, pt.z, qx, qy, qz);
          k0 = ((unsigned long long)__float_as_uint(d2) << 32) | pid;
        }
      }
      if (lane + 64 < T) {
        float4 pt = load_pt(sortb, false, lane + 64, Rr, s_pref, s_st);
        unsigned pid = __float_as_uint(pt.w);
        if (!(pid & 0x80000000u)) {
          float d2 = d2_exact(pt.x, pt.y, pt.z, qx, qy, qz);
          k1 = ((unsigned long long)__float_as_uint(d2) << 32) | pid;
        }
      }
      if (lane + 128 < T) {
        float4 pt = load_pt(sortb, false, lane + 128, Rr, s_pref, s_st);
        unsigned pid = __float_as_uint(pt.w);
        if (!(pid & 0x80000000u)) {
          float d2 = d2_exact(pt.x, pt.y, pt.z, qx, qy, qz);
          k2 = ((unsigned long long)__float_as_uint(d2) << 32) | pid;
        }
      }
      if (lane + 192 < T) {
        float4 pt = load_pt(sortb, false, lane + 192, Rr, s_pref, s_st);
        unsigned pid = __float_as_uint(pt.w);
        if (!(pid & 0x80000000u)) {
          float d2 = d2_exact(pt.x, pt.y, pt.z, qx, qy, qz);
          k3 = ((unsigned long long)__float_as_uint(d2) << 32) | pid;
        }
      }
      if (T <= 64) {
        k0 = bsort64(k0);
        if (lane < 17) s_top[lane] = k0;
      } else if (T <= 128) {
        bsort64x2(k0, k1);
        unsigned long long v = merge_sorted(k0, k1);
        if (lane < 17) s_top[lane] = v;
      } else if (T <= 192) {
        bsort64x3(k0, k1, k2);
        unsigned long long v = merge_sorted(k0, k1);
        v = merge_sorted(v, k2);
        if (lane < 17) s_top[lane] = v;
      } else {
        bsort64x4(k0, k1, k2, k3);
        unsigned long long v = merge_sorted(k0, k1);
        v = merge_sorted(v, k2);
        v = merge_sorted(v, k3);
        if (lane < 17) s_top[lane] = v;
      }
      __syncthreads();
      // merge side list (register keys; usually zero candidates within tau)
      unsigned long long tk = s_top[16];
      for (int guard = 0; guard < 4; ++guard) {
        if (lane == 0) s_cnt = 0;
        __syncthreads();
#pragma unroll
        for (int k = 0; k < 8; ++k) {
          if (skey[k] <= tk) {
            int q_ = atomicAdd(&s_cnt, 1);
            if (q_ < CAPM_) s_buf[q_] = skey[k];
          }
        }
        __syncthreads();
        int cnt = s_cnt;
        bool of = cnt > CAPM_;
        if (of) cnt = CAPM_;
        if (cnt == 0) break;
        if (lane < 17) s_buf[cnt + lane] = s_top[lane];
        __syncthreads();
        sel17(s_buf, cnt + 17, s_top, lane);
        __syncthreads();
        if (!of) break;
        tk = s_top[16];
      }
    } else {
      // GENERAL PATH (rare): pass1 lane-min -> tau, pass2 collect, sort
      unsigned long long lanemin = ~0ull;
      for (int p = lane; p < T; p += 64) {
        float4 pt = load_pt(sortb, brute, p, Rr, s_pref, s_st);
        unsigned pid = __float_as_uint(pt.w);
        if (pid & 0x80000000u) continue;
        float d2 = d2_exact(pt.x, pt.y, pt.z, qx, qy, qz);
        unsigned long long key =
            ((unsigned long long)__float_as_uint(d2) << 32) | pid;
        if (key < lanemin) lanemin = key;
      }
      unsigned long long sk = bsort64(lanemin);
      unsigned long long tauk = __shfl(sk, 16, 64);
      for (int guard = 0; guard < 8; ++guard) {
        if (lane == 0) s_cnt = 0;
        __syncthreads();
        for (int p = lane; p < T; p += 64) {
          float4 pt = load_pt(sortb, brute, p, Rr, s_pref, s_st);
          unsigned pid = __float_as_uint(pt.w);
          if (pid & 0x80000000u) continue;
          float d2 = d2_exact(pt.x, pt.y, pt.z, qx, qy, qz);
          unsigned long long key =
              ((unsigned long long)__float_as_uint(d2) << 32) | pid;
          if (key <= tauk) {
            int q_ = atomicAdd(&s_cnt, 1);
            if (q_ < CAPS_) s_buf[q_] = key;
          }
        }
#pragma unroll
        for (int k = 0; k < 8; ++k) {
          if (skey[k] <= tauk) {
            int q_ = atomicAdd(&s_cnt, 1);
            if (q_ < CAPS_) s_buf[q_] = skey[k];
          }
        }
        __syncthreads();
        int cntA = s_cnt;
        bool of = cntA > CAPS_;
        if (of) cntA = CAPS_;
        sel17(s_buf, cntA, s_top, lane);
        __syncthreads();
        if (!of) break;
        tauk = s_top[16];
      }
    }

    // ---- B2: shell cells (Chebyshev in (smin, eb]) with AABB lb <= tau ----
    bool doshell = false;
    int eb = 0;
    if (!brute) {
      float tf0 = __uint_as_float((unsigned)(s_top[16] >> 32));
      float trr = sqrtf(tf0);
      eb = (int)((trr + 1e-4f) * INVH_) + 1;
      if (eb > 31) eb = 31;
      doshell = eb > smin;
    }
    if (doshell) {
      unsigned long long tauk2 = s_top[16];
      for (int guard = 0; guard < 8; ++guard) {
        if (lane == 0) s_cnt = 0;
        __syncthreads();
        float tfc = __uint_as_float((unsigned)(tauk2 >> 32));
        int W2 = 2 * eb + 1, tot2 = W2 * W2 * W2;
        for (int o = lane; o < tot2; o += 64) {
          int oz = o / (W2 * W2), rem = o - oz * (W2 * W2);
          int oy = rem / W2, ox = rem - oy * W2;
          int ax = ox - eb, ay = oy - eb, az = oz - eb;
          int cax = ax < 0 ? -ax : ax, cay = ay < 0 ? -ay : ay,
              caz = az < 0 ? -az : az;
          int mx = cax > cay ? cax : cay;
          mx = mx > caz ? mx : caz;
          if (mx <= smin) continue;
          int ii = ci + ax, jj = cj + ay, kk = ck + az;
          if ((unsigned)ii >= GC_ || (unsigned)jj >= GC_ || (unsigned)kk >= GC_)
            continue;
          float lo, hi, d, dm = 0.f;
          lo = (ii == 0) ? -1e30f : LO_ + ii * H_ - 1e-5f;
          hi = (ii == GC_ - 1) ? 1e30f : LO_ + (ii + 1) * H_ + 1e-5f;
          d = (qx < lo) ? lo - qx : (qx > hi ? qx - hi : 0.f);
          dm += d * d;
          lo = (jj == 0) ? -1e30f : LO_ + jj * H_ - 1e-5f;
          hi = (jj == GC_ - 1) ? 1e30f : LO_ + (jj + 1) * H_ + 1e-5f;
          d = (qy < lo) ? lo - qy : (qy > hi ? qy - hi : 0.f);
          dm += d * d;
          lo = (kk == 0) ? -1e30f : LO_ + kk * H_ - 1e-5f;
          hi = (kk == GC_ - 1) ? 1e30f : LO_ + (kk + 1) * H_ + 1e-5f;
          d = (qz < lo) ? lo - qz : (qz > hi ? qz - hi : 0.f);
          dm += d * d;
          if (dm > tfc) continue;
          int cid = (ii * GC_ + jj) * GC_ + kk;
          int st = csb[cid], en = csb[cid + 1];
          for (int p = st; p < en; ++p) {
            float4 pt = sortb[p];
            unsigned pid = __float_as_uint(pt.w);
            if (pid & 0x80000000u) continue;
            float d2 = d2_exact(pt.x, pt.y, pt.z, qx, qy, qz);
            unsigned long long key =
                ((unsigned long long)__float_as_uint(d2) << 32) | pid;
            if (key <= tauk2) {
              int q_ = atomicAdd(&s_cnt, 1);
              if (q_ < CAPM_) s_buf[q_] = key;
            }
          }
        }
        __syncthreads();
        int cnt2 = s_cnt;
        bool of = cnt2 > CAPM_;
        if (of) cnt2 = CAPM_;
        if (cnt2 == 0) break;
        if (lane < 17) s_buf[cnt2 + lane] = s_top[lane];
        __syncthreads();
        sel17(s_buf, cnt2 + 17, s_top, lane);
        __syncthreads();
        if (!of) break;
        tauk2 = s_top[16];
      }
    }

    // ---- logits: batched butterfly (bitwise-identical per-neighbor tree) --
    __syncthreads();
    float pr[16];
    int nbs[16];
#pragma unroll
    for (int k = 0; k < 16; ++k) {
      unsigned nb = (unsigned)(s_top[k + 1] & 0xffffffffu) & (N_ - 1);
      nbs[k] = (int)nb;
      const float* fp = feats + ((size_t)b * N_ + nb) * 128;
      pr[k] = g0 * fp[lane] + g1 * fp[lane + 64];
    }
#pragma unroll
    for (int m = 1; m < 64; m <<= 1) {
#pragma unroll
      for (int k = 0; k < 16; ++k) pr[k] += __shfl_xor(pr[k], m, 64);
    }
    float bestv = -FLT_MAX;
    int bestn = nbs[0];
#pragma unroll
    for (int k = 0; k < 16; ++k) {
      float logit = (pr[k] + qbv) / sqrtf(128.0f);
      float tot = (logit + s_gum[k]) / 0.1f;
      if (tot > bestv) {
        bestv = tot;
        bestn = nbs[k];
      }
    }
    idx = bestn;
    walks[(size_t)g * 768 + (size_t)(l + 1) * 128 + lane] =
        feats[((size_t)b * N_ + idx) * 128 + lane];
    walks[(size_t)g * 768 + (size_t)(l + 1) * 128 + 64 + lane] =
        feats[((size_t)b * N_ + idx) * 128 + 64 + lane];
    __syncthreads();
  }
}

// ---------------- route + predict + scatter ----------------
// R5/R7/R8/R11 choreography verbatim; predict-phase s_x/s_hid aliased into
// sQ (dead by predict: last read in rt1, >=2 barriers earlier). LDS
// 55.5 -> 51.5 KB => 3 blocks/CU (was 2). launch_bounds(256,3) caps VGPR
// at ~170 (kernel uses <=92 - no spill).
#define DOT4(ACC, W0, W1, W2, W3, A)                           \
  ACC[0] += W0.x * A.x + W1.x * A.y + W2.x * A.z + W3.x * A.w; \
  ACC[1] += W0.y * A.x + W1.y * A.y + W2.y * A.z + W3.y * A.w; \
  ACC[2] += W0.z * A.x + W1.z * A.y + W2.z * A.z + W3.z * A.w; \
  ACC[3] += W0.w * A.x + W1.w * A.y + W2.w * A.z + W3.w * A.w;

__global__ __launch_bounds__(256, 3) void k_route(
    const float* __restrict__ curr, const float* __restrict__ prev,
    float* __restrict__ outw, const float* __restrict__ wT,
    const float* __restrict__ b_in, const float* __restrict__ b_out,
    const float* __restrict__ rt_b1, const float* __restrict__ rt_b2,
    const float* __restrict__ pw1, const float* __restrict__ pb1,
    const float* __restrict__ pw2, const float* __restrict__ pb2,
    const int* __restrict__ start, float* __restrict__ pos) {
  __shared__ __align__(16) float sA[4][768];
  __shared__ __align__(16) float sB[4][768];
  __shared__ __align__(16) float sQ[4][768];
  __shared__ __align__(16) float sK[4][768];
  __shared__ __align__(16) float s_att[4][144];
  // predict scratch aliased into sQ (dead by predict phase)
  float(*s_x)[256] = (float(*)[256]) & sQ[0][0];
  float(*s_hid)[64] = (float(*)[64])(&sQ[0][0] + 1024);

  const float4* wqT4 = (const float4*)(wT);
  const float4* wkT4 = (const float4*)(wT + 16384);
  const float4* wvT4 = (const float4*)(wT + 32768);
  const float4* woT4 = (const float4*)(wT + 3 * 16384);
  const float4* r1T4 = (const float4*)(wT + 4 * 16384);
  const float4* r2T4 = (const float4*)(wT + 5 * 16384);

  int g0 = blockIdx.x * 4, t = threadIdx.x;
  int b = g0 >> 9;
  int cg = t & 31, rg = t >> 5;
  int c0 = cg * 4;
  int wlk_[3], row_[3];
#pragma unroll
  for (int l = 0; l < 3; ++l) {
    int gr = rg * 3 + l;
    wlk_[l] = gr / 6;
    row_[l] = gr % 6;
  }
  {
    const float4* cg4 = (const float4*)(curr + (size_t)g0 * 768);
    const float4* pg4 = (const float4*)(prev + (size_t)g0 * 768);
    for (int i = t; i < 768; i += 256) {
      ((float4*)sA)[i] = cg4[i];
      ((float4*)sB)[i] = pg4[i];
    }
  }
  __syncthreads();

  float accq[3][4], acck[3][4], accv[3][4];
  {
    float4 bq4 = *(const float4*)&b_in[c0];
    float4 bk4 = *(const float4*)&b_in[128 + c0];
    float4 bv4 = *(const float4*)&b_in[256 + c0];
#pragma unroll
    for (int l = 0; l < 3; ++l) {
      accq[l][0] = bq4.x; accq[l][1] = bq4.y; accq[l][2] = bq4.z; accq[l][3] = bq4.w;
      acck[l][0] = bk4.x; acck[l][1] = bk4.y; acck[l][2] = bk4.z; acck[l][3] = bk4.w;
      accv[l][0] = bv4.x; accv[l][1] = bv4.y; accv[l][2] = bv4.z; accv[l][3] = bv4.w;
    }
  }
  for (int j = 0; j < 128; j += 4) {
    float4 q0 = wqT4[(j + 0) * 32 + cg], q1 = wqT4[(j + 1) * 32 + cg];
    float4 q2 = wqT4[(j + 2) * 32 + cg], q3 = wqT4[(j + 3) * 32 + cg];
    float4 k0 = wkT4[(j + 0) * 32 + cg], k1 = wkT4[(j + 1) * 32 + cg];
    float4 k2 = wkT4[(j + 2) * 32 + cg], k3 = wkT4[(j + 3) * 32 + cg];
    float4 v0 = wvT4[(j + 0) * 32 + cg], v1 = wvT4[(j + 1) * 32 + cg];
    float4 v2 = wvT4[(j + 2) * 32 + cg], v3 = wvT4[(j + 3) * 32 + cg];
#pragma unroll
    for (int l = 0; l < 3; ++l) {
      float4 ca = *(const float4*)&sA[wlk_[l]][row_[l] * 128 + j];
      float4 pa = *(const float4*)&sB[wlk_[l]][row_[l] * 128 + j];
      DOT4(accq[l], q0, q1, q2, q3, ca)
      DOT4(acck[l], k0, k1, k2, k3, pa)
      DOT4(accv[l], v0, v1, v2, v3, pa)
    }
  }
#pragma unroll
  for (int l = 0; l < 3; ++l) {
    *(float4*)&sQ[wlk_[l]][row_[l] * 128 + c0] =
        make_float4(accq[l][0], accq[l][1], accq[l][2], accq[l][3]);
    *(float4*)&sK[wlk_[l]][row_[l] * 128 + c0] =
        make_float4(acck[l][0], acck[l][1], acck[l][2], acck[l][3]);
  }
  __syncthreads();
#pragma unroll
  for (int l = 0; l < 3; ++l)
    *(float4*)&sB[wlk_[l]][row_[l] * 128 + c0] =
        make_float4(accv[l][0], accv[l][1], accv[l][2], accv[l][3]);
  __syncthreads();

  for (int e = t; e < 576; e += 256) {
    int wlk = e / 144, r = e % 144;
    int h = r / 36, rr = r % 36, i = rr / 6, jj = rr % 6;
    float acc = 0.f;
#pragma unroll
    for (int d = 0; d < 32; d += 4) {
      float4 q4 = *(const float4*)&sQ[wlk][i * 128 + h * 32 + d];
      float4 k4 = *(const float4*)&sK[wlk][jj * 128 + h * 32 + d];
      acc += q4.x * k4.x + q4.y * k4.y + q4.z * k4.z + q4.w * k4.w;
    }
    s_att[wlk][r] = acc / sqrtf(32.0f);
  }
  __syncthreads();
  if (t < 96) {
    int wlk = t / 24, r = t % 24;
    int h = r / 6, i = r % 6;
    float* row = &s_att[wlk][h * 36 + i * 6];
    float mx = row[0];
#pragma unroll
    for (int jj = 1; jj < 6; ++jj) mx = fmaxf(mx, row[jj]);
    float ex[6];
    float sum = 0.f;
#pragma unroll
    for (int jj = 0; jj < 6; ++jj) {
      ex[jj] = expf(row[jj] - mx);
      sum += ex[jj];
    }
#pragma unroll
    for (int jj = 0; jj < 6; ++jj) row[jj] = ex[jj] / sum;
  }
  __syncthreads();
  {
    int h = cg >> 3;
    float o[3][4];
#pragma unroll
    for (int l = 0; l < 3; ++l) {
      o[l][0] = 0.f; o[l][1] = 0.f; o[l][2] = 0.f; o[l][3] = 0.f;
#pragma unroll
      for (int jj = 0; jj < 6; ++jj) {
        float att = s_att[wlk_[l]][h * 36 + row_[l] * 6 + jj];
        float4 v4 = *(const float4*)&sB[wlk_[l]][jj * 128 + c0];
        o[l][0] += att * v4.x;
        o[l][1] += att * v4.y;
        o[l][2] += att * v4.z;
        o[l][3] += att * v4.w;
      }
    }
    __syncthreads();
#pragma unroll
    for (int l = 0; l < 3; ++l)
      *(float4*)&sA[wlk_[l]][row_[l] * 128 + c0] =
          make_float4(o[l][0], o[l][1], o[l][2], o[l][3]);
  }
  __syncthreads();

  float ao[3][4];
  {
    float4 b4 = *(const float4*)&b_out[c0];
#pragma unroll
    for (int l = 0; l < 3; ++l) {
      ao[l][0] = b4.x; ao[l][1] = b4.y; ao[l][2] = b4.z; ao[l][3] = b4.w;
    }
  }
  for (int j = 0; j < 128; j += 4) {
    float4 w0 = woT4[(j + 0) * 32 + cg], w1 = woT4[(j + 1) * 32 + cg];
    float4 w2 = woT4[(j + 2) * 32 + cg], w3 = woT4[(j + 3) * 32 + cg];
#pragma unroll
    for (int l = 0; l < 3; ++l) {
      float4 a4 = *(const float4*)&sA[wlk_[l]][row_[l] * 128 + j];
      DOT4(ao[l], w0, w1, w2, w3, a4)
    }
  }
  __syncthreads();
#pragma unroll
  for (int l = 0; l < 3; ++l)
    *(float4*)&sQ[wlk_[l]][row_[l] * 128 + c0] =
        make_float4(ao[l][0], ao[l][1], ao[l][2], ao[l][3]);
  __syncthreads();

  float a1[3][4];
  {
    float4 b4 = *(const float4*)&rt_b1[c0];
#pragma unroll
    for (int l = 0; l < 3; ++l) {
      a1[l][0] = b4.x; a1[l][1] = b4.y; a1[l][2] = b4.z; a1[l][3] = b4.w;
    }
  }
  for (int j = 0; j < 128; j += 4) {
    float4 w0 = r1T4[(j + 0) * 32 + cg], w1 = r1T4[(j + 1) * 32 + cg];
    float4 w2 = r1T4[(j + 2) * 32 + cg], w3 = r1T4[(j + 3) * 32 + cg];
#pragma unroll
    for (int l = 0; l < 3; ++l) {
      float4 a4 = *(const float4*)&sQ[wlk_[l]][row_[l] * 128 + j];
      DOT4(a1[l], w0, w1, w2, w3, a4)
    }
  }
  __syncthreads();
#pragma unroll
  for (int l = 0; l < 3; ++l)
    *(float4*)&sK[wlk_[l]][row_[l] * 128 + c0] =
        make_float4(fmaxf(a1[l][0], 0.f), fmaxf(a1[l][1], 0.f),
                    fmaxf(a1[l][2], 0.f), fmaxf(a1[l][3], 0.f));
  __syncthreads();

  float a2[3][4];
  {
    float4 b4 = *(const float4*)&rt_b2[c0];
#pragma unroll
    for (int l = 0; l < 3; ++l) {
      a2[l][0] = b4.x; a2[l][1] = b4.y; a2[l][2] = b4.z; a2[l][3] = b4.w;
    }
  }
  for (int j = 0; j < 128; j += 4) {
    float4 w0 = r2T4[(j + 0) * 32 + cg], w1 = r2T4[(j + 1) * 32 + cg];
    float4 w2 = r2T4[(j + 2) * 32 + cg], w3 = r2T4[(j + 3) * 32 + cg];
#pragma unroll
    for (int l = 0; l < 3; ++l) {
      float4 a4 = *(const float4*)&sK[wlk_[l]][row_[l] * 128 + j];
      DOT4(a2[l], w0, w1, w2, w3, a4)
    }
  }
  __syncthreads();
#pragma unroll
  for (int l = 0; l < 3; ++l) {
    float4 r4 = make_float4(a2[l][0], a2[l][1], a2[l][2], a2[l][3]);
    *(float4*)&outw[((size_t)(g0 + wlk_[l])) * 768 + row_[l] * 128 + c0] = r4;
    *(float4*)&sA[wlk_[l]][row_[l] * 128 + c0] = r4;
  }
  __syncthreads();

  for (int i = t; i < 512; i += 256) {
    int wlk = i >> 7, cc = i & 127;
    float sm = 0.f;
#pragma unroll
    for (int l = 1; l < 6; ++l) sm += sA[wlk][l * 128 + cc];
    s_x[wlk][cc] = sm / 5.0f - sA[wlk][cc];
    s_x[wlk][128 + cc] = sA[wlk][cc];
  }
  __syncthreads();
  {
    int wlk = t >> 6, h = t & 63;
    float acc = pb1[h];
#pragma unroll
    for (int j = 0; j < 256; j += 4) {
      float4 w4 = *(const float4*)&pw1[(size_t)h * 256 + j];
      float4 x4 = *(const float4*)&s_x[wlk][j];
      acc += w4.x * x4.x + w4.y * x4.y + w4.z * x4.z + w4.w * x4.w;
    }
    s_hid[wlk][h] = fmaxf(acc, 0.f);
  }
  __syncthreads();
  if (t < 12) {
    int wlk = t / 3, d = t % 3;
    float acc = pb2[d];
#pragma unroll
    for (int j = 0; j < 64; ++j) acc += pw2[d * 64 + j] * s_hid[wlk][j];
    float dd = tanhf(acc);
    int s = start[g0 + wlk];
    atomicAdd(&pos[((size_t)b * N_ + s) * 3 + d], dd);
  }
}

// ---------------- launcher ----------------
extern "C" void kernel_launch(void* const* d_in, const int* in_sizes, int n_in,
                              void* d_out, int out_size, void* d_ws,
                              size_t ws_size, hipStream_t stream) {
  const float* xyz = (const float*)d_in[0];
  const int* start = (const int*)d_in[1];
  const float* gumbel = (const float*)d_in[2];
  const float* enc_w1 = (const float*)d_in[3];
  const float* enc_b1 = (const float*)d_in[4];
  const float* enc_w2 = (const float*)d_in[5];
  const float* enc_b2 = (const float*)d_in[6];
  const float* beta_w = (const float*)d_in[7];
  const float* beta_b = (const float*)d_in[8];
  const float* gamma_w = (const float*)d_in[9];
  const float* gamma_b = (const float*)d_in[10];
  const float* attn_w_in = (const float*)d_in[11];
  const float* attn_b_in = (const float*)d_in[12];
  const float* attn_w_out = (const float*)d_in[13];
  const float* attn_b_out = (const float*)d_in[14];
  const float* rt_w1 = (const float*)d_in[15];
  const float* rt_b1 = (const float*)d_in[16];
  const float* rt_w2 = (const float*)d_in[17];
  const float* rt_b2 = (const float*)d_in[18];
  const float* pred_w1 = (const float*)d_in[19];
  const float* pred_b1 = (const float*)d_in[20];
  const float* pred_w2 = (const float*)d_in[21];
  const float* pred_b2 = (const float*)d_in[22];

  float* pos = (float*)d_out;
  float* ws = (float*)d_ws;
  float* feats = ws;
  float* qg = feats + (size_t)B_ * N_ * C_;
  float* qb = qg + (size_t)B_ * N_ * C_;
  float* wsel = qb + (size_t)B_ * N_;
  float* wA = wsel + (size_t)B_ * M_ * L_ * C_;
  float* wB = wA + (size_t)B_ * M_ * L_ * C_;
  float* wT = wB + (size_t)B_ * M_ * L_ * C_;
  float4* sorted = (float4*)(wT + 6 * 16384);
  float4* posM = sorted + (size_t)B_ * N_;
  int* flags = (int*)(posM + B_ * M_);   // reused as `claim` later
  int* counts = flags + B_ * N_;         // reused as cellCur
  int* countsU = counts + B_ * NC_;
  int* cellStart = countsU + B_ * NC_;
  int* cellCur = counts;  // alias (per-thread ownership in k_gprefix)
  int* claim = flags;     // alias (flags dead after grid build)

  hipMemcpyAsync(pos, xyz, (size_t)B_ * N_ * 3 * sizeof(float),
                 hipMemcpyDeviceToDevice, stream);
  hipMemsetAsync(flags, 0, (size_t)B_ * N_ * sizeof(int), stream);
  hipMemsetAsync(counts, 0, (size_t)B_ * NC_ * sizeof(int), stream);
  hipMemsetAsync(countsU, 0, (size_t)B_ * NC_ * sizeof(int), stream);

  k_encode<<<2048, 256, 0, stream>>>(xyz, enc_w1, enc_b1, enc_w2, enc_b2,
                                     feats);
  k_prep<<<dim3(64, 6), 256, 0, stream>>>(attn_w_in, attn_w_out, rt_w1, rt_w2,
                                          wT);
  k_mv1<<<2048, 256, 0, stream>>>(feats, beta_w, beta_b, qg);
  k_mv2<<<2048, 256, 0, stream>>>(qg, gamma_w, gamma_b, qb);
  k_flags<<<8, 256, 0, stream>>>(start, flags);
  k_gcount<<<256, 256, 0, stream>>>(xyz, flags, counts, countsU);
  k_gprefix<<<4, 256, 0, stream>>>(counts, cellStart, cellCur);
  k_gscatter<<<256, 256, 0, stream>>>(xyz, flags, cellCur, sorted);
  // claim zeroed ONCE; per-step dedup uses distinct tags 1..5 (flags region
  // is dead after grid build; zero guarantees tag!=stale on step 0)
  hipMemsetAsync(claim, 0, (size_t)B_ * N_ * sizeof(int), stream);

  float* prevbuf = wsel;
  for (int t = 0; t < STEPS_; ++t) {
    k_side<<<8, 256, 0, stream>>>(pos, start, claim, posM, t + 1);
    const float* gptr = gumbel + (size_t)t * (L_ - 1) * B_ * M_ * K_;
    k_select5<<<2048, 64, 0, stream>>>(pos, feats, qg, qb, start, wsel, sorted,
                                       cellStart, countsU, posM, gptr);
    float* ob = (t & 1) ? wB : wA;
    k_route<<<512, 256, 0, stream>>>(
        wsel, prevbuf, ob, wT, attn_b_in, attn_b_out, rt_b1, rt_b2, pred_w1,
        pred_b1, pred_w2, pred_b2, start, pos);
    prevbuf = ob;
  }
}

// Round 14
// 1361.283 us; speedup vs baseline: 1.0400x; 1.0400x over previous
//
#include <hip/hip_runtime.h>
#include <cfloat>
#include <cmath>

#define B_ 4
#define N_ 16384
#define M_ 512
#define C_ 128
#define K_ 16
#define L_ 6
#define STEPS_ 5

#define GC_ 32
#define NC_ (GC_ * GC_ * GC_)
#define LO_ (-5.2f)
#define H_ (10.4f / 32.0f)
#define INVH_ (32.0f / 10.4f)
#define CAPS_ 192
#define CAPM_ 175

// ---------------- wave helpers (wave64) ----------------
__device__ inline int wave_sum_i(int v) {
#pragma unroll
  for (int m = 1; m < 64; m <<= 1) v += __shfl_xor(v, m, 64);
  return v;
}
__device__ __forceinline__ unsigned long long bsort64(unsigned long long v) {
  int lane = threadIdx.x & 63;
#pragma unroll
  for (int k = 2; k <= 64; k <<= 1) {
#pragma unroll
    for (int j = k >> 1; j > 0; j >>= 1) {
      unsigned long long o = __shfl_xor(v, j, 64);
      bool keepmin = (((lane & k) == 0) == ((lane & j) == 0));
      unsigned long long mn = v < o ? v : o;
      unsigned long long mx = v < o ? o : v;
      v = keepmin ? mn : mx;
    }
  }
  return v;
}
__device__ __forceinline__ void bsort64x2(unsigned long long& v0,
                                          unsigned long long& v1) {
  int lane = threadIdx.x & 63;
#pragma unroll
  for (int k = 2; k <= 64; k <<= 1) {
#pragma unroll
    for (int j = k >> 1; j > 0; j >>= 1) {
      bool keepmin = (((lane & k) == 0) == ((lane & j) == 0));
      unsigned long long o0 = __shfl_xor(v0, j, 64);
      unsigned long long o1 = __shfl_xor(v1, j, 64);
      v0 = keepmin ? (v0 < o0 ? v0 : o0) : (v0 < o0 ? o0 : v0);
      v1 = keepmin ? (v1 < o1 ? v1 : o1) : (v1 < o1 ? o1 : v1);
    }
  }
}
__device__ __forceinline__ void bsort64x3(unsigned long long& v0,
                                          unsigned long long& v1,
                                          unsigned long long& v2) {
  int lane = threadIdx.x & 63;
#pragma unroll
  for (int k = 2; k <= 64; k <<= 1) {
#pragma unroll
    for (int j = k >> 1; j > 0; j >>= 1) {
      bool keepmin = (((lane & k) == 0) == ((lane & j) == 0));
      unsigned long long o0 = __shfl_xor(v0, j, 64);
      unsigned long long o1 = __shfl_xor(v1, j, 64);
      unsigned long long o2 = __shfl_xor(v2, j, 64);
      v0 = keepmin ? (v0 < o0 ? v0 : o0) : (v0 < o0 ? o0 : v0);
      v1 = keepmin ? (v1 < o1 ? v1 : o1) : (v1 < o1 ? o1 : v1);
      v2 = keepmin ? (v2 < o2 ? v2 : o2) : (v2 < o2 ? o2 : v2);
    }
  }
}
__device__ __forceinline__ void bsort64x4(unsigned long long& v0,
                                          unsigned long long& v1,
                                          unsigned long long& v2,
                                          unsigned long long& v3) {
  int lane = threadIdx.x & 63;
#pragma unroll
  for (int k = 2; k <= 64; k <<= 1) {
#pragma unroll
    for (int j = k >> 1; j > 0; j >>= 1) {
      bool keepmin = (((lane & k) == 0) == ((lane & j) == 0));
      unsigned long long o0 = __shfl_xor(v0, j, 64);
      unsigned long long o1 = __shfl_xor(v1, j, 64);
      unsigned long long o2 = __shfl_xor(v2, j, 64);
      unsigned long long o3 = __shfl_xor(v3, j, 64);
      v0 = keepmin ? (v0 < o0 ? v0 : o0) : (v0 < o0 ? o0 : v0);
      v1 = keepmin ? (v1 < o1 ? v1 : o1) : (v1 < o1 ? o1 : v1);
      v2 = keepmin ? (v2 < o2 ? v2 : o2) : (v2 < o2 ? o2 : v2);
      v3 = keepmin ? (v3 < o3 ? v3 : o3) : (v3 < o3 ? o3 : v3);
    }
  }
}
// merge two cross-lane-sorted ascending sequences (top-17 valid in each)
__device__ __forceinline__ unsigned long long merge_sorted(
    unsigned long long acc, unsigned long long neu) {
  int lane = threadIdx.x & 63;
  unsigned long long hi = __shfl(neu, 63 - lane, 64);
  unsigned long long v = (lane < 32) ? acc : hi;
#pragma unroll
  for (int j = 32; j > 0; j >>= 1) {
    unsigned long long o = __shfl_xor(v, j, 64);
    unsigned long long mn = v < o ? v : o;
    unsigned long long mx = v < o ? o : v;
    v = ((lane & j) == 0) ? mn : mx;
  }
  return v;
}
// exact smallest-17 of s_buf[0..cnt), cnt <= 192 (pure-shuffle tournament)
__device__ __forceinline__ void sel17(const unsigned long long* s_buf, int cnt,
                                      unsigned long long* s_out, int lane) {
  unsigned long long v0 = (lane < cnt) ? s_buf[lane] : ~0ull;
  if (cnt <= 64) {
    v0 = bsort64(v0);
    if (lane < 17) s_out[lane] = v0;
    return;
  }
  unsigned long long v1 = (lane + 64 < cnt) ? s_buf[lane + 64] : ~0ull;
  if (cnt <= 128) {
    bsort64x2(v0, v1);
    unsigned long long v = merge_sorted(v0, v1);
    if (lane < 17) s_out[lane] = v;
    return;
  }
  unsigned long long v2 = (lane + 128 < cnt) ? s_buf[lane + 128] : ~0ull;
  bsort64x3(v0, v1, v2);
  unsigned long long v = merge_sorted(v0, v1);
  v = merge_sorted(v, v2);
  if (lane < 17) s_out[lane] = v;
}
__device__ __forceinline__ float d2_exact(float px, float py, float pz,
                                          float qx, float qy, float qz) {
#pragma clang fp contract(off)
  float dx = px - qx, dy = py - qy, dz = pz - qz;
  float xx = dx * dx, yy = dy * dy, zz = dz * dz;
  return (xx + yy) + zz;
}
__device__ __forceinline__ int cell_of(float x) {
  int c = (int)floorf((x - LO_) * INVH_);
  return c < 0 ? 0 : (c > GC_ - 1 ? GC_ - 1 : c);
}

// ---------------- encoder ----------------
__global__ __launch_bounds__(256) void k_encode(
    const float* __restrict__ xyz, const float* __restrict__ w1,
    const float* __restrict__ b1, const float* __restrict__ w2,
    const float* __restrict__ b2, float* __restrict__ feats) {
  __shared__ __align__(16) float s_w2[128 * 68];
  __shared__ __align__(16) float s_xyz[32 * 3];
  __shared__ __align__(16) float s_h[32 * 68];
  int t = threadIdx.x;
  for (int i = t; i < 128 * 64; i += 256) {
    int c = i >> 6, j = i & 63;
    s_w2[c * 68 + j] = w2[i];
  }
  int p0 = blockIdx.x * 32;
  for (int i = t; i < 96; i += 256) s_xyz[i] = xyz[(size_t)p0 * 3 + i];
  __syncthreads();
  int p = t >> 3, q = t & 7;
  float x0 = s_xyz[p * 3], x1 = s_xyz[p * 3 + 1], x2 = s_xyz[p * 3 + 2];
#pragma unroll
  for (int cc = 0; cc < 8; ++cc) {
    int c = q * 8 + cc;
    float a = b1[c] + w1[c * 3] * x0 + w1[c * 3 + 1] * x1 + w1[c * 3 + 2] * x2;
    s_h[p * 68 + c] = fmaxf(a, 0.f);
  }
  __syncthreads();
#pragma unroll
  for (int cc = 0; cc < 16; ++cc) {
    int c = q + cc * 8;
    float acc = b2[c];
    const float* wr = &s_w2[c * 68];
    const float* hr = &s_h[p * 68];
#pragma unroll
    for (int j = 0; j < 64; j += 4) {
      float4 w4 = *(const float4*)&wr[j];
      float4 h4 = *(const float4*)&hr[j];
      acc += w4.x * h4.x + w4.y * h4.y + w4.z * h4.z + w4.w * h4.w;
    }
    feats[(size_t)(p0 + p) * 128 + c] = acc;
  }
}

// ---------------- weight transpose prep ----------------
__global__ __launch_bounds__(256) void k_prep(
    const float* __restrict__ w_in, const float* __restrict__ w_out,
    const float* __restrict__ rt_w1, const float* __restrict__ rt_w2,
    float* __restrict__ wT) {
  int m = blockIdx.y;
  int i = blockIdx.x * 256 + threadIdx.x;
  int j = i >> 7, c = i & 127;
  const float* src = (m == 0)   ? w_in
                     : (m == 1) ? w_in + 16384
                     : (m == 2) ? w_in + 32768
                     : (m == 3) ? w_out
                     : (m == 4) ? rt_w1
                                : rt_w2;
  wT[(size_t)m * 16384 + j * 128 + c] = src[(size_t)c * 128 + j];
}

// ---------------- mv1: q = feats @ beta^T + beta_b ----------------
__global__ __launch_bounds__(256) void k_mv1(const float* __restrict__ feats,
                                             const float* __restrict__ beta_w,
                                             const float* __restrict__ beta_b,
                                             float* __restrict__ qbuf) {
  __shared__ __align__(16) float s_ft[32 * 128];
  int t = threadIdx.x;
  size_t p0 = (size_t)blockIdx.x * 32;
  const float4* src = (const float4*)(feats + p0 * 128);
  for (int i = t; i < 1024; i += 256) ((float4*)s_ft)[i] = src[i];
  __syncthreads();
  int c = t & 127, ph = t >> 7;
  float acc[16];
  float bb = beta_b[c];
#pragma unroll
  for (int i = 0; i < 16; ++i) acc[i] = bb;
  for (int j = 0; j < 128; j += 4) {
    float4 w4 = *(const float4*)&beta_w[(size_t)c * 128 + j];
#pragma unroll
    for (int i = 0; i < 16; ++i) {
      float4 f4 = *(const float4*)&s_ft[(ph * 16 + i) * 128 + j];
      acc[i] += w4.x * f4.x + w4.y * f4.y + w4.z * f4.z + w4.w * f4.w;
    }
  }
#pragma unroll
  for (int i = 0; i < 16; ++i) qbuf[(p0 + ph * 16 + i) * 128 + c] = acc[i];
}

// ---------------- mv2: qg = q @ gamma (in-place), qb = tree(q.gamma_b) ----
__global__ __launch_bounds__(256) void k_mv2(float* __restrict__ qbuf,
                                             const float* __restrict__ gamma_w,
                                             const float* __restrict__ gamma_b,
                                             float* __restrict__ qb) {
  __shared__ __align__(16) float s_t[32 * 128];
  __shared__ __align__(16) float s_gb[128];
  int t = threadIdx.x;
  size_t p0 = (size_t)blockIdx.x * 32;
  const float4* src = (const float4*)(qbuf + p0 * 128);
  for (int i = t; i < 1024; i += 256) ((float4*)s_t)[i] = src[i];
  if (t < 128) s_gb[t] = gamma_b[t];
  __syncthreads();
  int c = t & 127, ph = t >> 7;
  float acc[16];
#pragma unroll
  for (int i = 0; i < 16; ++i) acc[i] = 0.f;
  for (int cp = 0; cp < 128; ++cp) {
    float gw = gamma_w[(size_t)cp * 128 + c];
#pragma unroll
    for (int i = 0; i < 16; ++i) acc[i] += s_t[(ph * 16 + i) * 128 + cp] * gw;
  }
#pragma unroll
  for (int i = 0; i < 16; ++i) qbuf[(p0 + ph * 16 + i) * 128 + c] = acc[i];
  if (t < 32) {
    const float* tr = &s_t[t * 128];
    float x[32];
#pragma unroll
    for (int i = 0; i < 32; ++i) {
      float a = tr[2 * i] * s_gb[2 * i] + tr[2 * i + 64] * s_gb[2 * i + 64];
      float b2 = tr[2 * i + 1] * s_gb[2 * i + 1] +
                 tr[2 * i + 65] * s_gb[2 * i + 65];
      x[i] = a + b2;
    }
#pragma unroll
    for (int w2 = 16; w2 >= 1; w2 >>= 1)
      for (int i = 0; i < w2; ++i) x[i] = x[2 * i] + x[2 * i + 1];
    qb[p0 + t] = x[0];
  }
}

// ---------------- grid build ----------------
__global__ __launch_bounds__(256) void k_flags(const int* __restrict__ start,
                                               int* __restrict__ flags) {
  int g = blockIdx.x * 256 + threadIdx.x;
  if (g < B_ * M_) {
    int b = g >> 9;
    flags[b * N_ + start[g]] = 1;
  }
}
__global__ __launch_bounds__(256) void k_gcount(const float* __restrict__ xyz,
                                                const int* __restrict__ flags,
                                                int* __restrict__ counts,
                                                int* __restrict__ countsU) {
  int i = blockIdx.x * 256 + threadIdx.x;
  int b = i >> 14;
  float x = xyz[(size_t)i * 3], y = xyz[(size_t)i * 3 + 1],
        z = xyz[(size_t)i * 3 + 2];
  int cid = (cell_of(x) * GC_ + cell_of(y)) * GC_ + cell_of(z);
  atomicAdd(&counts[b * NC_ + cid], 1);
  if (!flags[i]) atomicAdd(&countsU[b * NC_ + cid], 1);
}
__global__ __launch_bounds__(256) void k_gprefix(const int* __restrict__ counts,
                                                 int* __restrict__ cellStart,
                                                 int* __restrict__ cellCur) {
  __shared__ int part[256];
  int b = blockIdx.x, t = threadIdx.x;
  const int* cb = counts + b * NC_;
  int s = 0;
  for (int k = 0; k < NC_ / 256; ++k) s += cb[t * (NC_ / 256) + k];
  part[t] = s;
  __syncthreads();
  if (t == 0) {
    int r = 0;
    for (int i = 0; i < 256; ++i) {
      int v = part[i];
      part[i] = r;
      r += v;
    }
  }
  __syncthreads();
  int run = part[t];
  for (int k = 0; k < NC_ / 256; ++k) {
    int cidx = t * (NC_ / 256) + k;
    int v = cb[cidx];
    cellStart[b * (NC_ + 1) + cidx] = run;
    cellCur[b * NC_ + cidx] = run;
    run += v;
  }
  if (t == 255) cellStart[b * (NC_ + 1) + NC_] = run;
}
__global__ __launch_bounds__(256) void k_gscatter(const float* __restrict__ xyz,
                                                  const int* __restrict__ flags,
                                                  int* __restrict__ cellCur,
                                                  float4* __restrict__ sorted) {
  int i = blockIdx.x * 256 + threadIdx.x;
  int b = i >> 14, n = i & (N_ - 1);
  float x = xyz[(size_t)i * 3], y = xyz[(size_t)i * 3 + 1],
        z = xyz[(size_t)i * 3 + 2];
  int cid = (cell_of(x) * GC_ + cell_of(y)) * GC_ + cell_of(z);
  int dst = atomicAdd(&cellCur[b * NC_ + cid], 1);
  unsigned pid = (unsigned)n | (flags[i] ? 0x80000000u : 0u);
  sorted[(size_t)b * N_ + dst] = make_float4(x, y, z, __uint_as_float(pid));
}
// per-step side list; dedup via atomicExch step-tag (claim zeroed once per
// launch; tags 1..5 are distinct per step and never equal stale values)
__global__ __launch_bounds__(256) void k_side(const float* __restrict__ pos,
                                              const int* __restrict__ start,
                                              int* __restrict__ claim,
                                              float4* __restrict__ posM,
                                              int tag) {
  int g = blockIdx.x * 256 + threadIdx.x;
  if (g < B_ * M_) {
    int b = g >> 9, s = start[g];
    int old = atomicExch(&claim[b * N_ + s], tag);
    if (old != tag) {
      const float* pp = pos + ((size_t)b * N_ + s) * 3;
      posM[g] = make_float4(pp[0], pp[1], pp[2], __uint_as_float((unsigned)s));
    } else {
      posM[g] = make_float4(3e30f, 3e30f, 3e30f, __uint_as_float(0xffffffffu));
    }
  }
}

// point lookup: row = largest r with s_pref[r] <= p; clamped index
__device__ __forceinline__ float4 load_pt(const float4* sortb, bool brute,
                                          int p, int Rr,
                                          const int* s_pref, const int* s_st) {
  int off;
  if (brute) {
    off = p;
  } else if (Rr == 1) {
    off = s_st[0] + p;  // dense-center fast path (smin==0)
  } else {
    int lo = 0, hi = Rr - 1, rsel = 0;
    while (lo <= hi) {
      int mid = (lo + hi) >> 1;
      if (s_pref[mid] <= p) {
        rsel = mid;
        lo = mid + 1;
      } else
        hi = mid - 1;
    }
    off = s_st[rsel] + (p - s_pref[rsel]);
  }
  off = off < 0 ? 0 : (off > N_ - 1 ? N_ - 1 : off);
  return sortb[off];
}

// ---------------- fused selector: 5 rounds, 1 walker per 64-thread block ---
__global__ __launch_bounds__(64) void k_select5(
    const float* __restrict__ pos, const float* __restrict__ feats,
    const float* __restrict__ qg, const float* __restrict__ qbArr,
    const int* __restrict__ start, float* __restrict__ walks,
    const float4* __restrict__ sorted, const int* __restrict__ cellStart,
    const int* __restrict__ countsU, const float4* __restrict__ posM,
    const float* __restrict__ gumb) {
  __shared__ int s_st[232];
  __shared__ int s_pref[232];
  __shared__ unsigned long long s_buf[CAPS_ + 24];
  __shared__ unsigned long long s_top[17];
  __shared__ float s_gum[16];
  __shared__ int s_cnt;

  int lane = threadIdx.x;
  int g = blockIdx.x;
  int b = g >> 9, mm = g & (M_ - 1);
  int idx = start[g];
  walks[(size_t)g * 768 + lane] = feats[((size_t)b * N_ + idx) * 128 + lane];
  walks[(size_t)g * 768 + 64 + lane] =
      feats[((size_t)b * N_ + idx) * 128 + 64 + lane];

  const float4* sortb = sorted + (size_t)b * N_;
  const int* csb = cellStart + b * (NC_ + 1);
  const int* cub = countsU + b * NC_;

  for (int l = 0; l < L_ - 1; ++l) {
    float g0 = qg[((size_t)b * N_ + idx) * 128 + lane];
    float g1 = qg[((size_t)b * N_ + idx) * 128 + 64 + lane];
    float qbv = qbArr[(size_t)b * N_ + idx];
    const float* pp = pos + ((size_t)b * N_ + idx) * 3;
    float qx = pp[0], qy = pp[1], qz = pp[2];
    if (lane < 16)
      s_gum[lane] =
          gumb[(size_t)l * B_ * M_ * K_ + ((size_t)b * M_ + mm) * K_ + lane];
    // prefetch side list into registers (loads overlap phase A below)
    float4 sp[8];
#pragma unroll
    for (int k = 0; k < 8; ++k) sp[k] = posM[(b << 9) + lane + (k << 6)];
    __syncthreads();

    int ci = cell_of(qx), cj = cell_of(qy), ck = cell_of(qz);

    // ---- phase A: rings 0-2 in one pass; rare s=3..7 via early-exit ----
    int smin = -1, acc = 0;
    {
      int p0 = 0, p1 = 0, p2 = 0;
#pragma unroll
      for (int it = 0; it < 2; ++it) {
        int o = it * 64 + lane;
        if (o < 125) {
          int oz = o / 25, rem = o - oz * 25;
          int oy = rem / 5, ox = rem - oy * 5;
          int ax = ox - 2, ay = oy - 2, az = oz - 2;
          int cax = ax < 0 ? -ax : ax, cay = ay < 0 ? -ay : ay,
              caz = az < 0 ? -az : az;
          int ring = cax > cay ? cax : cay;
          ring = ring > caz ? ring : caz;
          int ii = ci + ax, jj = cj + ay, kk = ck + az;
          if ((unsigned)ii < GC_ && (unsigned)jj < GC_ && (unsigned)kk < GC_) {
            int cnt = cub[(ii * GC_ + jj) * GC_ + kk];
            if (ring == 0) p0 += cnt;
            else if (ring == 1) p1 += cnt;
            else p2 += cnt;
          }
        }
      }
#pragma unroll
      for (int m = 1; m < 64; m <<= 1) {
        p0 += __shfl_xor(p0, m, 64);
        p1 += __shfl_xor(p1, m, 64);
        p2 += __shfl_xor(p2, m, 64);
      }
      int u0 = p0, u1 = p0 + p1, u2 = u1 + p2;
      smin = (u0 >= 17) ? 0 : (u1 >= 17) ? 1 : (u2 >= 17) ? 2 : -1;
      acc = u2;
    }
    for (int s = 3; s <= 7 && smin < 0; ++s) {
      int Wd = 2 * s + 1, tot = Wd * Wd * Wd;
      int part = 0;
      for (int o = lane; o < tot; o += 64) {
        int oz = o / (Wd * Wd), rem = o - oz * (Wd * Wd);
        int oy = rem / Wd, ox = rem - oy * Wd;
        int ax = ox - s, ay = oy - s, az = oz - s;
        int cax = ax < 0 ? -ax : ax, cay = ay < 0 ? -ay : ay,
            caz = az < 0 ? -az : az;
        int mx = cax > cay ? cax : cay;
        mx = mx > caz ? mx : caz;
        if (mx != s) continue;
        int ii = ci + ax, jj = cj + ay, kk = ck + az;
        if ((unsigned)ii >= GC_ || (unsigned)jj >= GC_ || (unsigned)kk >= GC_)
          continue;
        part += cub[(ii * GC_ + jj) * GC_ + kk];
      }
      acc += wave_sum_i(part);
      if (acc >= 17) smin = s;
    }
    bool brute = smin < 0;

    // side keys from prefetched registers (pure ALU, no loads)
    unsigned long long skey[8];
#pragma unroll
    for (int k = 0; k < 8; ++k) {
      unsigned pid = __float_as_uint(sp[k].w);
      float d2s = d2_exact(sp[k].x, sp[k].y, sp[k].z, qx, qy, qz);
      skey[k] = (pid == 0xffffffffu)
                    ? ~0ull
                    : (((unsigned long long)__float_as_uint(d2s) << 32) | pid);
    }

    // ---- build z-run table for the cube ----
    int T = 0, Rr = 0;
    if (!brute) {
      int Wd = 2 * smin + 1;
      Rr = Wd * Wd;
      int klo = ck - smin, khi = ck + smin;
      if (klo < 0) klo = 0;
      if (khi > GC_ - 1) khi = GC_ - 1;
      int nch = (Rr + 63) >> 6;
      for (int c = 0; c < nch; ++c) {
        int r = c * 64 + lane;
        int len = 0, st = 0;
        if (r < Rr) {
          int di = r / Wd, dj = r - di * Wd;
          int ii = ci + di - smin, jj = cj + dj - smin;
          if ((unsigned)ii < GC_ && (unsigned)jj < GC_) {
            int base = (ii * GC_ + jj) * GC_;
            st = csb[base + klo];
            len = csb[base + khi + 1] - st;
          }
        }
        int scan = len;
#pragma unroll
        for (int off = 1; off < 64; off <<= 1) {
          int v = __shfl_up(scan, off, 64);
          if (lane >= off) scan += v;
        }
        if (r < Rr) {
          s_pref[r] = T + scan - len;
          s_st[r] = st;
        }
        T += __shfl(scan, 63, 64);
      }
      __syncthreads();
    } else {
      T = N_;
    }

    // ---- B1 ----
    if (!brute && T <= 256) {
      // DIRECT PATH: single scan -> registers -> pure-shuffle tournament.
      unsigned long long k0 = ~0ull, k1 = ~0ull, k2 = ~0ull, k3 = ~0ull;
      if (lane < T) {
        float4 pt = load_pt(sortb, false, lane, Rr, s_pref, s_st);
        unsigned pid = __float_as_uint(pt.w);
        if (!(pid & 0x80000000u)) {
          float d2 = d2_exact(pt.x, pt.y, pt.z, qx, qy, qz);
          k0 = ((unsigned long long)__float_as_uint(d2) << 32) | pid;
        }
      }
      if (lane + 64 < T) {
        float4 pt = load_pt(sortb, false, lane + 64, Rr, s_pref, s_st);
        unsigned pid = __float_as_uint(pt.w);
        if (!(pid & 0x80000000u)) {
          float d2 = d2_exact(pt.x, pt.y, pt.z, qx, qy, qz);
          k1 = ((unsigned long long)__float_as_uint(d2) << 32) | pid;
        }
      }
      if (lane + 128 < T) {
        float4 pt = load_pt(sortb, false, lane + 128, Rr, s_pref, s_st);
        unsigned pid = __float_as_uint(pt.w);
        if (!(pid & 0x80000000u)) {
          float d2 = d2_exact(pt.x, pt.y, pt.z, qx, qy, qz);
          k2 = ((unsigned long long)__float_as_uint(d2) << 32) | pid;
        }
      }
      if (lane + 192 < T) {
        float4 pt = load_pt(sortb, false, lane + 192, Rr, s_pref, s_st);
        unsigned pid = __float_as_uint(pt.w);
        if (!(pid & 0x80000000u)) {
          float d2 = d2_exact(pt.x, pt.y, pt.z, qx, qy, qz);
          k3 = ((unsigned long long)__float_as_uint(d2) << 32) | pid;
        }
      }
      if (T <= 64) {
        k0 = bsort64(k0);
        if (lane < 17) s_top[lane] = k0;
      } else if (T <= 128) {
        bsort64x2(k0, k1);
        unsigned long long v = merge_sorted(k0, k1);
        if (lane < 17) s_top[lane] = v;
      } else if (T <= 192) {
        bsort64x3(k0, k1, k2);
        unsigned long long v = merge_sorted(k0, k1);
        v = merge_sorted(v, k2);
        if (lane < 17) s_top[lane] = v;
      } else {
        bsort64x4(k0, k1, k2, k3);
        unsigned long long v = merge_sorted(k0, k1);
        v = merge_sorted(v, k2);
        v = merge_sorted(v, k3);
        if (lane < 17) s_top[lane] = v;
      }
      __syncthreads();
      // merge side list (register keys; usually zero candidates within tau)
      unsigned long long tk = s_top[16];
      for (int guard = 0; guard < 4; ++guard) {
        if (lane == 0) s_cnt = 0;
        __syncthreads();
#pragma unroll
        for (int k = 0; k < 8; ++k) {
          if (skey[k] <= tk) {
            int q_ = atomicAdd(&s_cnt, 1);
            if (q_ < CAPM_) s_buf[q_] = skey[k];
          }
        }
        __syncthreads();
        int cnt = s_cnt;
        bool of = cnt > CAPM_;
        if (of) cnt = CAPM_;
        if (cnt == 0) break;
        if (lane < 17) s_buf[cnt + lane] = s_top[lane];
        __syncthreads();
        sel17(s_buf, cnt + 17, s_top, lane);
        __syncthreads();
        if (!of) break;
        tk = s_top[16];
      }
    } else {
      // GENERAL PATH (rare): pass1 lane-min -> tau, pass2 collect, sort
      unsigned long long lanemin = ~0ull;
      for (int p = lane; p < T; p += 64) {
        float4 pt = load_pt(sortb, brute, p, Rr, s_pref, s_st);
        unsigned pid = __float_as_uint(pt.w);
        if (pid & 0x80000000u) continue;
        float d2 = d2_exact(pt.x, pt.y, pt.z, qx, qy, qz);
        unsigned long long key =
            ((unsigned long long)__float_as_uint(d2) << 32) | pid;
        if (key < lanemin) lanemin = key;
      }
      unsigned long long sk = bsort64(lanemin);
      unsigned long long tauk = __shfl(sk, 16, 64);
      for (int guard = 0; guard < 8; ++guard) {
        if (lane == 0) s_cnt = 0;
        __syncthreads();
        for (int p = lane; p < T; p += 64) {
          float4 pt = load_pt(sortb, brute, p, Rr, s_pref, s_st);
          unsigned pid = __float_as_uint(pt.w);
          if (pid & 0x80000000u) continue;
          float d2 = d2_exact(pt.x, pt.y, pt.z, qx, qy, qz);
          unsigned long long key =
              ((unsigned long long)__float_as_uint(d2) << 32) | pid;
          if (key <= tauk) {
            int q_ = atomicAdd(&s_cnt, 1);
            if (q_ < CAPS_) s_buf[q_] = key;
          }
        }
#pragma unroll
        for (int k = 0; k < 8; ++k) {
          if (skey[k] <= tauk) {
            int q_ = atomicAdd(&s_cnt, 1);
            if (q_ < CAPS_) s_buf[q_] = skey[k];
          }
        }
        __syncthreads();
        int cntA = s_cnt;
        bool of = cntA > CAPS_;
        if (of) cntA = CAPS_;
        sel17(s_buf, cntA, s_top, lane);
        __syncthreads();
        if (!of) break;
        tauk = s_top[16];
      }
    }

    // ---- B2: shell cells (Chebyshev in (smin, eb]) with AABB lb <= tau ----
    bool doshell = false;
    int eb = 0;
    if (!brute) {
      float tf0 = __uint_as_float((unsigned)(s_top[16] >> 32));
      float trr = sqrtf(tf0);
      eb = (int)((trr + 1e-4f) * INVH_) + 1;
      if (eb > 31) eb = 31;
      doshell = eb > smin;
    }
    if (doshell) {
      unsigned long long tauk2 = s_top[16];
      for (int guard = 0; guard < 8; ++guard) {
        if (lane == 0) s_cnt = 0;
        __syncthreads();
        float tfc = __uint_as_float((unsigned)(tauk2 >> 32));
        int W2 = 2 * eb + 1, tot2 = W2 * W2 * W2;
        for (int o = lane; o < tot2; o += 64) {
          int oz = o / (W2 * W2), rem = o - oz * (W2 * W2);
          int oy = rem / W2, ox = rem - oy * W2;
          int ax = ox - eb, ay = oy - eb, az = oz - eb;
          int cax = ax < 0 ? -ax : ax, cay = ay < 0 ? -ay : ay,
              caz = az < 0 ? -az : az;
          int mx = cax > cay ? cax : cay;
          mx = mx > caz ? mx : caz;
          if (mx <= smin) continue;
          int ii = ci + ax, jj = cj + ay, kk = ck + az;
          if ((unsigned)ii >= GC_ || (unsigned)jj >= GC_ || (unsigned)kk >= GC_)
            continue;
          float lo, hi, d, dm = 0.f;
          lo = (ii == 0) ? -1e30f : LO_ + ii * H_ - 1e-5f;
          hi = (ii == GC_ - 1) ? 1e30f : LO_ + (ii + 1) * H_ + 1e-5f;
          d = (qx < lo) ? lo - qx : (qx > hi ? qx - hi : 0.f);
          dm += d * d;
          lo = (jj == 0) ? -1e30f : LO_ + jj * H_ - 1e-5f;
          hi = (jj == GC_ - 1) ? 1e30f : LO_ + (jj + 1) * H_ + 1e-5f;
          d = (qy < lo) ? lo - qy : (qy > hi ? qy - hi : 0.f);
          dm += d * d;
          lo = (kk == 0) ? -1e30f : LO_ + kk * H_ - 1e-5f;
          hi = (kk == GC_ - 1) ? 1e30f : LO_ + (kk + 1) * H_ + 1e-5f;
          d = (qz < lo) ? lo - qz : (qz > hi ? qz - hi : 0.f);
          dm += d * d;
          if (dm > tfc) continue;
          int cid = (ii * GC_ + jj) * GC_ + kk;
          int st = csb[cid], en = csb[cid + 1];
          for (int p = st; p < en; ++p) {
            float4 pt = sortb[p];
            unsigned pid = __float_as_uint(pt.w);
            if (pid & 0x80000000u) continue;
            float d2 = d2_exact(pt.x, pt.y, pt.z, qx, qy, qz);
            unsigned long long key =
                ((unsigned long long)__float_as_uint(d2) << 32) | pid;
            if (key <= tauk2) {
              int q_ = atomicAdd(&s_cnt, 1);
              if (q_ < CAPM_) s_buf[q_] = key;
            }
          }
        }
        __syncthreads();
        int cnt2 = s_cnt;
        bool of = cnt2 > CAPM_;
        if (of) cnt2 = CAPM_;
        if (cnt2 == 0) break;
        if (lane < 17) s_buf[cnt2 + lane] = s_top[lane];
        __syncthreads();
        sel17(s_buf, cnt2 + 17, s_top, lane);
        __syncthreads();
        if (!of) break;
        tauk2 = s_top[16];
      }
    }

    // ---- logits: batched butterfly (bitwise-identical per-neighbor tree) --
    __syncthreads();
    float pr[16];
    int nbs[16];
#pragma unroll
    for (int k = 0; k < 16; ++k) {
      unsigned nb = (unsigned)(s_top[k + 1] & 0xffffffffu) & (N_ - 1);
      nbs[k] = (int)nb;
      const float* fp = feats + ((size_t)b * N_ + nb) * 128;
      pr[k] = g0 * fp[lane] + g1 * fp[lane + 64];
    }
#pragma unroll
    for (int m = 1; m < 64; m <<= 1) {
#pragma unroll
      for (int k = 0; k < 16; ++k) pr[k] += __shfl_xor(pr[k], m, 64);
    }
    float bestv = -FLT_MAX;
    int bestn = nbs[0];
#pragma unroll
    for (int k = 0; k < 16; ++k) {
      float logit = (pr[k] + qbv) / sqrtf(128.0f);
      float tot = (logit + s_gum[k]) / 0.1f;
      if (tot > bestv) {
        bestv = tot;
        bestn = nbs[k];
      }
    }
    idx = bestn;
    walks[(size_t)g * 768 + (size_t)(l + 1) * 128 + lane] =
        feats[((size_t)b * N_ + idx) * 128 + lane];
    walks[(size_t)g * 768 + (size_t)(l + 1) * 128 + 64 + lane] =
        feats[((size_t)b * N_ + idx) * 128 + 64 + lane];
    __syncthreads();
  }
}

// ---------------- route + predict + scatter (R12-verbatim, best measured) --
#define DOT4(ACC, W0, W1, W2, W3, A)                           \
  ACC[0] += W0.x * A.x + W1.x * A.y + W2.x * A.z + W3.x * A.w; \
  ACC[1] += W0.y * A.x + W1.y * A.y + W2.y * A.z + W3.y * A.w; \
  ACC[2] += W0.z * A.x + W1.z * A.y + W2.z * A.z + W3.z * A.w; \
  ACC[3] += W0.w * A.x + W1.w * A.y + W2.w * A.z + W3.w * A.w;

__global__ __launch_bounds__(256, 2) void k_route(
    const float* __restrict__ curr, const float* __restrict__ prev,
    float* __restrict__ outw, const float* __restrict__ wT,
    const float* __restrict__ b_in, const float* __restrict__ b_out,
    const float* __restrict__ rt_b1, const float* __restrict__ rt_b2,
    const float* __restrict__ pw1, const float* __restrict__ pb1,
    const float* __restrict__ pw2, const float* __restrict__ pb2,
    const int* __restrict__ start, float* __restrict__ pos) {
  __shared__ __align__(16) float sA[4][768];
  __shared__ __align__(16) float sB[4][768];
  __shared__ __align__(16) float sQ[4][768];
  __shared__ __align__(16) float sK[4][768];
  __shared__ __align__(16) float s_att[4][144];
  __shared__ __align__(16) float s_x[4][256];
  __shared__ __align__(16) float s_hid[4][64];

  const float4* wqT4 = (const float4*)(wT);
  const float4* wkT4 = (const float4*)(wT + 16384);
  const float4* wvT4 = (const float4*)(wT + 32768);
  const float4* woT4 = (const float4*)(wT + 3 * 16384);
  const float4* r1T4 = (const float4*)(wT + 4 * 16384);
  const float4* r2T4 = (const float4*)(wT + 5 * 16384);

  int g0 = blockIdx.x * 4, t = threadIdx.x;
  int b = g0 >> 9;
  int cg = t & 31, rg = t >> 5;
  int c0 = cg * 4;
  int wlk_[3], row_[3];
#pragma unroll
  for (int l = 0; l < 3; ++l) {
    int gr = rg * 3 + l;
    wlk_[l] = gr / 6;
    row_[l] = gr % 6;
  }
  {
    const float4* cg4 = (const float4*)(curr + (size_t)g0 * 768);
    const float4* pg4 = (const float4*)(prev + (size_t)g0 * 768);
    for (int i = t; i < 768; i += 256) {
      ((float4*)sA)[i] = cg4[i];
      ((float4*)sB)[i] = pg4[i];
    }
  }
  __syncthreads();

  float accq[3][4], acck[3][4], accv[3][4];
  {
    float4 bq4 = *(const float4*)&b_in[c0];
    float4 bk4 = *(const float4*)&b_in[128 + c0];
    float4 bv4 = *(const float4*)&b_in[256 + c0];
#pragma unroll
    for (int l = 0; l < 3; ++l) {
      accq[l][0] = bq4.x; accq[l][1] = bq4.y; accq[l][2] = bq4.z; accq[l][3] = bq4.w;
      acck[l][0] = bk4.x; acck[l][1] = bk4.y; acck[l][2] = bk4.z; acck[l][3] = bk4.w;
      accv[l][0] = bv4.x; accv[l][1] = bv4.y; accv[l][2] = bv4.z; accv[l][3] = bv4.w;
    }
  }
  for (int j = 0; j < 128; j += 4) {
    float4 q0 = wqT4[(j + 0) * 32 + cg], q1 = wqT4[(j + 1) * 32 + cg];
    float4 q2 = wqT4[(j + 2) * 32 + cg], q3 = wqT4[(j + 3) * 32 + cg];
    float4 k0 = wkT4[(j + 0) * 32 + cg], k1 = wkT4[(j + 1) * 32 + cg];
    float4 k2 = wkT4[(j + 2) * 32 + cg], k3 = wkT4[(j + 3) * 32 + cg];
    float4 v0 = wvT4[(j + 0) * 32 + cg], v1 = wvT4[(j + 1) * 32 + cg];
    float4 v2 = wvT4[(j + 2) * 32 + cg], v3 = wvT4[(j + 3) * 32 + cg];
#pragma unroll
    for (int l = 0; l < 3; ++l) {
      float4 ca = *(const float4*)&sA[wlk_[l]][row_[l] * 128 + j];
      float4 pa = *(const float4*)&sB[wlk_[l]][row_[l] * 128 + j];
      DOT4(accq[l], q0, q1, q2, q3, ca)
      DOT4(acck[l], k0, k1, k2, k3, pa)
      DOT4(accv[l], v0, v1, v2, v3, pa)
    }
  }
#pragma unroll
  for (int l = 0; l < 3; ++l) {
    *(float4*)&sQ[wlk_[l]][row_[l] * 128 + c0] =
        make_float4(accq[l][0], accq[l][1], accq[l][2], accq[l][3]);
    *(float4*)&sK[wlk_[l]][row_[l] * 128 + c0] =
        make_float4(acck[l][0], acck[l][1], acck[l][2], acck[l][3]);
  }
  __syncthreads();
#pragma unroll
  for (int l = 0; l < 3; ++l)
    *(float4*)&sB[wlk_[l]][row_[l] * 128 + c0] =
        make_float4(accv[l][0], accv[l][1], accv[l][2], accv[l][3]);
  __syncthreads();

  for (int e = t; e < 576; e += 256) {
    int wlk = e / 144, r = e % 144;
    int h = r / 36, rr = r % 36, i = rr / 6, jj = rr % 6;
    float acc = 0.f;
#pragma unroll
    for (int d = 0; d < 32; d += 4) {
      float4 q4 = *(const float4*)&sQ[wlk][i * 128 + h * 32 + d];
      float4 k4 = *(const float4*)&sK[wlk][jj * 128 + h * 32 + d];
      acc += q4.x * k4.x + q4.y * k4.y + q4.z * k4.z + q4.w * k4.w;
    }
    s_att[wlk][r] = acc / sqrtf(32.0f);
  }
  __syncthreads();
  if (t < 96) {
    int wlk = t / 24, r = t % 24;
    int h = r / 6, i = r % 6;
    float* row = &s_att[wlk][h * 36 + i * 6];
    float mx = row[0];
#pragma unroll
    for (int jj = 1; jj < 6; ++jj) mx = fmaxf(mx, row[jj]);
    float ex[6];
    float sum = 0.f;
#pragma unroll
    for (int jj = 0; jj < 6; ++jj) {
      ex[jj] = expf(row[jj] - mx);
      sum += ex[jj];
    }
#pragma unroll
    for (int jj = 0; jj < 6; ++jj) row[jj] = ex[jj] / sum;
  }
  __syncthreads();
  {
    int h = cg >> 3;
    float o[3][4];
#pragma unroll
    for (int l = 0; l < 3; ++l) {
      o[l][0] = 0.f; o[l][1] = 0.f; o[l][2] = 0.f; o[l][3] = 0.f;
#pragma unroll
      for (int jj = 0; jj < 6; ++jj) {
        float att = s_att[wlk_[l]][h * 36 + row_[l] * 6 + jj];
        float4 v4 = *(const float4*)&sB[wlk_[l]][jj * 128 + c0];
        o[l][0] += att * v4.x;
        o[l][1] += att * v4.y;
        o[l][2] += att * v4.z;
        o[l][3] += att * v4.w;
      }
    }
    __syncthreads();
#pragma unroll
    for (int l = 0; l < 3; ++l)
      *(float4*)&sA[wlk_[l]][row_[l] * 128 + c0] =
          make_float4(o[l][0], o[l][1], o[l][2], o[l][3]);
  }
  __syncthreads();

  float ao[3][4];
  {
    float4 b4 = *(const float4*)&b_out[c0];
#pragma unroll
    for (int l = 0; l < 3; ++l) {
      ao[l][0] = b4.x; ao[l][1] = b4.y; ao[l][2] = b4.z; ao[l][3] = b4.w;
    }
  }
  for (int j = 0; j < 128; j += 4) {
    float4 w0 = woT4[(j + 0) * 32 + cg], w1 = woT4[(j + 1) * 32 + cg];
    float4 w2 = woT4[(j + 2) * 32 + cg], w3 = woT4[(j + 3) * 32 + cg];
#pragma unroll
    for (int l = 0; l < 3; ++l) {
      float4 a4 = *(const float4*)&sA[wlk_[l]][row_[l] * 128 + j];
      DOT4(ao[l], w0, w1, w2, w3, a4)
    }
  }
  __syncthreads();
#pragma unroll
  for (int l = 0; l < 3; ++l)
    *(float4*)&sQ[wlk_[l]][row_[l] * 128 + c0] =
        make_float4(ao[l][0], ao[l][1], ao[l][2], ao[l][3]);
  __syncthreads();

  float a1[3][4];
  {
    float4 b4 = *(const float4*)&rt_b1[c0];
#pragma unroll
    for (int l = 0; l < 3; ++l) {
      a1[l][0] = b4.x; a1[l][1] = b4.y; a1[l][2] = b4.z; a1[l][3] = b4.w;
    }
  }
  for (int j = 0; j < 128; j += 4) {
    float4 w0 = r1T4[(j + 0) * 32 + cg], w1 = r1T4[(j + 1) * 32 + cg];
    float4 w2 = r1T4[(j + 2) * 32 + cg], w3 = r1T4[(j + 3) * 32 + cg];
#pragma unroll
    for (int l = 0; l < 3; ++l) {
      float4 a4 = *(const float4*)&sQ[wlk_[l]][row_[l] * 128 + j];
      DOT4(a1[l], w0, w1, w2, w3, a4)
    }
  }
  __syncthreads();
#pragma unroll
  for (int l = 0; l < 3; ++l)
    *(float4*)&sK[wlk_[l]][row_[l] * 128 + c0] =
        make_float4(fmaxf(a1[l][0], 0.f), fmaxf(a1[l][1], 0.f),
                    fmaxf(a1[l][2], 0.f), fmaxf(a1[l][3], 0.f));
  __syncthreads();

  float a2[3][4];
  {
    float4 b4 = *(const float4*)&rt_b2[c0];
#pragma unroll
    for (int l = 0; l < 3; ++l) {
      a2[l][0] = b4.x; a2[l][1] = b4.y; a2[l][2] = b4.z; a2[l][3] = b4.w;
    }
  }
  for (int j = 0; j < 128; j += 4) {
    float4 w0 = r2T4[(j + 0) * 32 + cg], w1 = r2T4[(j + 1) * 32 + cg];
    float4 w2 = r2T4[(j + 2) * 32 + cg], w3 = r2T4[(j + 3) * 32 + cg];
#pragma unroll
    for (int l = 0; l < 3; ++l) {
      float4 a4 = *(const float4*)&sK[wlk_[l]][row_[l] * 128 + j];
      DOT4(a2[l], w0, w1, w2, w3, a4)
    }
  }
  __syncthreads();
#pragma unroll
  for (int l = 0; l < 3; ++l) {
    float4 r4 = make_float4(a2[l][0], a2[l][1], a2[l][2], a2[l][3]);
    *(float4*)&outw[((size_t)(g0 + wlk_[l])) * 768 + row_[l] * 128 + c0] = r4;
    *(float4*)&sA[wlk_[l]][row_[l] * 128 + c0] = r4;
  }
  __syncthreads();

  for (int i = t; i < 512; i += 256) {
    int wlk = i >> 7, cc = i & 127;
    float sm = 0.f;
#pragma unroll
    for (int l = 1; l < 6; ++l) sm += sA[wlk][l * 128 + cc];
    s_x[wlk][cc] = sm / 5.0f - sA[wlk][cc];
    s_x[wlk][128 + cc] = sA[wlk][cc];
  }
  __syncthreads();
  {
    int wlk = t >> 6, h = t & 63;
    float acc = pb1[h];
#pragma unroll
    for (int j = 0; j < 256; j += 4) {
      float4 w4 = *(const float4*)&pw1[(size_t)h * 256 + j];
      float4 x4 = *(const float4*)&s_x[wlk][j];
      acc += w4.x * x4.x + w4.y * x4.y + w4.z * x4.z + w4.w * x4.w;
    }
    s_hid[wlk][h] = fmaxf(acc, 0.f);
  }
  __syncthreads();
  if (t < 12) {
    int wlk = t / 3, d = t % 3;
    float acc = pb2[d];
#pragma unroll
    for (int j = 0; j < 64; ++j) acc += pw2[d * 64 + j] * s_hid[wlk][j];
    float dd = tanhf(acc);
    int s = start[g0 + wlk];
    atomicAdd(&pos[((size_t)b * N_ + s) * 3 + d], dd);
  }
}

// ---------------- launcher ----------------
extern "C" void kernel_launch(void* const* d_in, const int* in_sizes, int n_in,
                              void* d_out, int out_size, void* d_ws,
                              size_t ws_size, hipStream_t stream) {
  const float* xyz = (const float*)d_in[0];
  const int* start = (const int*)d_in[1];
  const float* gumbel = (const float*)d_in[2];
  const float* enc_w1 = (const float*)d_in[3];
  const float* enc_b1 = (const float*)d_in[4];
  const float* enc_w2 = (const float*)d_in[5];
  const float* enc_b2 = (const float*)d_in[6];
  const float* beta_w = (const float*)d_in[7];
  const float* beta_b = (const float*)d_in[8];
  const float* gamma_w = (const float*)d_in[9];
  const float* gamma_b = (const float*)d_in[10];
  const float* attn_w_in = (const float*)d_in[11];
  const float* attn_b_in = (const float*)d_in[12];
  const float* attn_w_out = (const float*)d_in[13];
  const float* attn_b_out = (const float*)d_in[14];
  const float* rt_w1 = (const float*)d_in[15];
  const float* rt_b1 = (const float*)d_in[16];
  const float* rt_w2 = (const float*)d_in[17];
  const float* rt_b2 = (const float*)d_in[18];
  const float* pred_w1 = (const float*)d_in[19];
  const float* pred_b1 = (const float*)d_in[20];
  const float* pred_w2 = (const float*)d_in[21];
  const float* pred_b2 = (const float*)d_in[22];

  float* pos = (float*)d_out;
  float* ws = (float*)d_ws;
  float* feats = ws;
  float* qg = feats + (size_t)B_ * N_ * C_;
  float* qb = qg + (size_t)B_ * N_ * C_;
  float* wsel = qb + (size_t)B_ * N_;
  float* wA = wsel + (size_t)B_ * M_ * L_ * C_;
  float* wB = wA + (size_t)B_ * M_ * L_ * C_;
  float* wT = wB + (size_t)B_ * M_ * L_ * C_;
  float4* sorted = (float4*)(wT + 6 * 16384);
  float4* posM = sorted + (size_t)B_ * N_;
  int* flags = (int*)(posM + B_ * M_);   // reused as `claim` later
  int* counts = flags + B_ * N_;         // reused as cellCur
  int* countsU = counts + B_ * NC_;
  int* cellStart = countsU + B_ * NC_;
  int* cellCur = counts;  // alias (per-thread ownership in k_gprefix)
  int* claim = flags;     // alias (flags dead after grid build)

  hipMemcpyAsync(pos, xyz, (size_t)B_ * N_ * 3 * sizeof(float),
                 hipMemcpyDeviceToDevice, stream);
  hipMemsetAsync(flags, 0, (size_t)B_ * N_ * sizeof(int), stream);
  hipMemsetAsync(counts, 0, (size_t)B_ * NC_ * sizeof(int), stream);
  hipMemsetAsync(countsU, 0, (size_t)B_ * NC_ * sizeof(int), stream);

  k_encode<<<2048, 256, 0, stream>>>(xyz, enc_w1, enc_b1, enc_w2, enc_b2,
                                     feats);
  k_prep<<<dim3(64, 6), 256, 0, stream>>>(attn_w_in, attn_w_out, rt_w1, rt_w2,
                                          wT);
  k_mv1<<<2048, 256, 0, stream>>>(feats, beta_w, beta_b, qg);
  k_mv2<<<2048, 256, 0, stream>>>(qg, gamma_w, gamma_b, qb);
  k_flags<<<8, 256, 0, stream>>>(start, flags);
  k_gcount<<<256, 256, 0, stream>>>(xyz, flags, counts, countsU);
  k_gprefix<<<4, 256, 0, stream>>>(counts, cellStart, cellCur);
  k_gscatter<<<256, 256, 0, stream>>>(xyz, flags, cellCur, sorted);
  // claim zeroed ONCE; per-step dedup uses distinct tags 1..5
  hipMemsetAsync(claim, 0, (size_t)B_ * N_ * sizeof(int), stream);

  float* prevbuf = wsel;
  for (int t = 0; t < STEPS_; ++t) {
    k_side<<<8, 256, 0, stream>>>(pos, start, claim, posM, t + 1);
    const float* gptr = gumbel + (size_t)t * (L_ - 1) * B_ * M_ * K_;
    k_select5<<<2048, 64, 0, stream>>>(pos, feats, qg, qb, start, wsel, sorted,
                                       cellStart, countsU, posM, gptr);
    float* ob = (t & 1) ? wB : wA;
    k_route<<<512, 256, 0, stream>>>(
        wsel, prevbuf, ob, wT, attn_b_in, attn_b_out, rt_b1, rt_b2, pred_w1,
        pred_b1, pred_w2, pred_b2, start, pos);
    prevbuf = ob;
  }
}